// Round 16
// baseline (180.458 us; speedup 1.0000x reference)
//
#include <hip/hip_runtime.h>

typedef __attribute__((ext_vector_type(8))) short s16x8;
typedef __attribute__((ext_vector_type(4))) float fx4;
typedef __attribute__((ext_vector_type(4))) int ix4;

#define B_SZ 4
#define T_SZ 2048
#define DM 1024
#define NH 16
#define DK 64
#define M_SZ (B_SZ * T_SZ)   // 8192
#define NINF (-__builtin_inff())
#define QSCALE (0.125f * 1.44269504088896340736f)
#define MAX3(a,b,c) fmaxf(fmaxf(a,b),c)

__device__ __forceinline__ unsigned short f2bf(float f) {
    unsigned int u = __float_as_uint(f);
    unsigned int r = u + 0x7fffu + ((u >> 16) & 1u);
    return (unsigned short)(r >> 16);
}

__device__ __forceinline__ unsigned cvtpk(float lo, float hi) {
    unsigned r;
    asm("v_cvt_pk_bf16_f32 %0, %1, %2" : "=v"(r) : "v"(lo), "v"(hi));
    return r;
}

__device__ __forceinline__ void async16(const unsigned short* g, unsigned short* l) {
    __builtin_amdgcn_global_load_lds(
        (const __attribute__((address_space(1))) unsigned int*)g,
        (__attribute__((address_space(3))) unsigned int*)l, 16, 0, 0);
}

// raw workgroup barrier WITHOUT the __syncthreads vmcnt(0) drain.
__device__ __forceinline__ void barrier_nodrain() {
    asm volatile("" ::: "memory");
    __builtin_amdgcn_s_barrier();
    asm volatile("" ::: "memory");
}

// ---------------- merged cast: y==0 -> x (8.4M), y==1..4 -> weights ----------------
__global__ void cast_all(const float* __restrict__ x,
                         const float* __restrict__ s1, const float* __restrict__ s2,
                         const float* __restrict__ s3, const float* __restrict__ s4,
                         unsigned short* __restrict__ xb, unsigned short* __restrict__ wb) {
    const int y = blockIdx.y;
    const float* s;
    unsigned short* d;
    int n;
    if (y == 0) { s = x; d = xb; n = M_SZ * DM; }
    else {
        s = (y == 1) ? s1 : (y == 2) ? s2 : (y == 3) ? s3 : s4;
        d = wb + (size_t)(y - 1) * (DM * DM);
        n = DM * DM;
    }
    int i = (blockIdx.x * blockDim.x + threadIdx.x) * 4;
    int stride = gridDim.x * blockDim.x * 4;
    for (; i + 3 < n; i += stride) {
        float4 v = *(const float4*)(s + i);
        ushort4 o;
        o.x = f2bf(v.x); o.y = f2bf(v.y); o.z = f2bf(v.z); o.w = f2bf(v.w);
        *(ushort4*)(d + i) = o;
    }
}

// ---------------- fused QKV GEMM: 128x256 tile, BK=64, 3-buffer 2-deep pipeline ----------------
// stage(kt+2) -> vmcnt(12) [only tile kt's 6 loads remain required] -> raw barrier ->
// compute(buf kt%3) -> raw barrier.  ~2 compute phases of slack covers HBM-miss latency.
__global__ __launch_bounds__(512, 2) void gemm_qkv256(const unsigned short* __restrict__ A,
                                                      const unsigned short* __restrict__ W,
                                                      unsigned short* __restrict__ Qs,
                                                      unsigned short* __restrict__ Kb,
                                                      unsigned short* __restrict__ Vt) {
    // A bufs (128x64): elems 0 / 8192 / 16384 ; B bufs (256x64): 24576 + i*16384. 144 KB.
    __shared__ __align__(16) unsigned short S[73728];

    const int t = threadIdx.x;
    const int lane = t & 63, w = t >> 6;
    const int wm = w >> 2, wn = w & 3;          // 2 x 4 wave grid
    const int lrow = lane & 15, lk = lane >> 4;
    const int bx = blockIdx.x;                  // 0..11
    const int m0 = blockIdx.y * 128;
    const int K = DM;
    const int NKT = K / 64;                     // 16

    fx4 acc[4][4] = {};

    const int srow = t >> 3;                    // 0..63
    const int cs = (t & 7) ^ (srow & 7);        // swizzled source chunk
    const unsigned short* Ag = A + (long)(m0 + srow) * K + cs * 8;
    const unsigned short* Bg = W + (long)(bx * 256 + srow) * K + cs * 8;

    // prologue: tiles 0 -> buf0, 1 -> buf1
#pragma unroll
    for (int pt = 0; pt < 2; ++pt) {
        const int ko = pt * 64;
        const int nbA = pt * 8192;
        const int nbB = 24576 + pt * 16384;
        async16(Ag + ko,           &S[nbA + t * 8]);
        async16(Ag + 64 * K + ko,  &S[nbA + 4096 + t * 8]);
        async16(Bg + ko,           &S[nbB + t * 8]);
        async16(Bg + 64 * K + ko,  &S[nbB + 4096 + t * 8]);
        async16(Bg + 128 * K + ko, &S[nbB + 8192 + t * 8]);
        async16(Bg + 192 * K + ko, &S[nbB + 12288 + t * 8]);
    }

    int cur = 0;                                // buffer holding tile kt
    for (int kt = 0; kt < NKT; ++kt) {
        if (kt + 2 < NKT) {
            int stg = cur + 2; if (stg >= 3) stg -= 3;
            const int ko = (kt + 2) * 64;
            const int nbA = stg * 8192;
            const int nbB = 24576 + stg * 16384;
            async16(Ag + ko,           &S[nbA + t * 8]);
            async16(Ag + 64 * K + ko,  &S[nbA + 4096 + t * 8]);
            async16(Bg + ko,           &S[nbB + t * 8]);
            async16(Bg + 64 * K + ko,  &S[nbB + 4096 + t * 8]);
            async16(Bg + 128 * K + ko, &S[nbB + 8192 + t * 8]);
            async16(Bg + 192 * K + ko, &S[nbB + 12288 + t * 8]);
            asm volatile("s_waitcnt vmcnt(12)" ::: "memory");   // tile kt's loads landed
        } else if (kt + 1 < NKT) {
            asm volatile("s_waitcnt vmcnt(6)" ::: "memory");
        } else {
            asm volatile("s_waitcnt vmcnt(0)" ::: "memory");
        }
        barrier_nodrain();                                      // buf[cur] ready block-wide
        const unsigned short* Ab = &S[cur * 8192];
        const unsigned short* Bb = &S[24576 + cur * 16384];
#pragma unroll
        for (int kk = 0; kk < 2; ++kk) {
            const int sw = ((kk * 4 + lk) ^ (lrow & 7)) * 8;
            s16x8 af[4], bf[4];
#pragma unroll
            for (int mf = 0; mf < 4; ++mf)
                af[mf] = *(const s16x8*)&Ab[(wm * 64 + mf * 16 + lrow) * 64 + sw];
#pragma unroll
            for (int nf = 0; nf < 4; ++nf)
                bf[nf] = *(const s16x8*)&Bb[(wn * 64 + nf * 16 + lrow) * 64 + sw];
            __builtin_amdgcn_s_setprio(1);
#pragma unroll
            for (int mf = 0; mf < 4; ++mf)
#pragma unroll
                for (int nf = 0; nf < 4; ++nf)
                    acc[mf][nf] = __builtin_amdgcn_mfma_f32_16x16x32_bf16(af[mf], bf[nf], acc[mf][nf], 0, 0, 0);
            __builtin_amdgcn_s_setprio(0);
        }
        barrier_nodrain();                                      // reads of buf[cur] done
        cur = (cur + 1 == 3) ? 0 : cur + 1;
    }

    const int which = bx >> 2;
    const int n0l = (bx & 3) * 256;
    if (which < 2) {
        unsigned short* dst = which ? Kb : Qs;
        const float sc = which ? 1.f : QSCALE;
#pragma unroll
        for (int mf = 0; mf < 4; ++mf)
#pragma unroll
            for (int nf = 0; nf < 4; ++nf)
#pragma unroll
                for (int r = 0; r < 4; ++r) {
                    int row = m0 + wm * 64 + mf * 16 + lk * 4 + r;
                    int col = n0l + wn * 64 + nf * 16 + lrow;
                    dst[(long)row * DM + col] = f2bf(acc[mf][nf][r] * sc);
                }
    } else {
#pragma unroll
        for (int mf = 0; mf < 4; ++mf)
#pragma unroll
            for (int nf = 0; nf < 4; ++nf) {
                const int cl = wn * 64 + nf * 16 + lrow;
                const int rl = wm * 64 + mf * 16 + lk * 4;
                ushort4 pk;
                pk.x = f2bf(acc[mf][nf][0]); pk.y = f2bf(acc[mf][nf][1]);
                pk.z = f2bf(acc[mf][nf][2]); pk.w = f2bf(acc[mf][nf][3]);
                *(ushort4*)&S[cl * 132 + rl] = pk;
            }
        __syncthreads();
        const int c = t >> 1, h2 = t & 1;
        unsigned short* vtp = Vt + (long)(n0l + c) * M_SZ + m0 + h2 * 64;
#pragma unroll
        for (int j = 0; j < 8; ++j) {
            union { struct { ushort4 a, b; } s; ix4 v; } u;
            u.s.a = *(const ushort4*)&S[c * 132 + h2 * 64 + j * 8];
            u.s.b = *(const ushort4*)&S[c * 132 + h2 * 64 + j * 8 + 4];
            *(ix4*)(vtp + j * 8) = u.v;
        }
    }
}

// ---------------- output GEMM: same 3-buffer pipeline, fp32 epilogue ----------------
__global__ __launch_bounds__(512, 2) void gemm_out256(const unsigned short* __restrict__ A,
                                                      const unsigned short* __restrict__ W,
                                                      float* __restrict__ C) {
    __shared__ __align__(16) unsigned short S[73728];   // 144 KB

    const int t = threadIdx.x;
    const int lane = t & 63, w = t >> 6;
    const int wm = w >> 2, wn = w & 3;
    const int lrow = lane & 15, lk = lane >> 4;
    const int n0 = blockIdx.x * 256;
    const int m0 = blockIdx.y * 128;
    const int K = DM;
    const int NKT = K / 64;

    fx4 acc[4][4] = {};

    const int srow = t >> 3;
    const int cs = (t & 7) ^ (srow & 7);
    const unsigned short* Ag = A + (long)(m0 + srow) * K + cs * 8;
    const unsigned short* Bg = W + (long)(n0 + srow) * K + cs * 8;

#pragma unroll
    for (int pt = 0; pt < 2; ++pt) {
        const int ko = pt * 64;
        const int nbA = pt * 8192;
        const int nbB = 24576 + pt * 16384;
        async16(Ag + ko,           &S[nbA + t * 8]);
        async16(Ag + 64 * K + ko,  &S[nbA + 4096 + t * 8]);
        async16(Bg + ko,           &S[nbB + t * 8]);
        async16(Bg + 64 * K + ko,  &S[nbB + 4096 + t * 8]);
        async16(Bg + 128 * K + ko, &S[nbB + 8192 + t * 8]);
        async16(Bg + 192 * K + ko, &S[nbB + 12288 + t * 8]);
    }

    int cur = 0;
    for (int kt = 0; kt < NKT; ++kt) {
        if (kt + 2 < NKT) {
            int stg = cur + 2; if (stg >= 3) stg -= 3;
            const int ko = (kt + 2) * 64;
            const int nbA = stg * 8192;
            const int nbB = 24576 + stg * 16384;
            async16(Ag + ko,           &S[nbA + t * 8]);
            async16(Ag + 64 * K + ko,  &S[nbA + 4096 + t * 8]);
            async16(Bg + ko,           &S[nbB + t * 8]);
            async16(Bg + 64 * K + ko,  &S[nbB + 4096 + t * 8]);
            async16(Bg + 128 * K + ko, &S[nbB + 8192 + t * 8]);
            async16(Bg + 192 * K + ko, &S[nbB + 12288 + t * 8]);
            asm volatile("s_waitcnt vmcnt(12)" ::: "memory");
        } else if (kt + 1 < NKT) {
            asm volatile("s_waitcnt vmcnt(6)" ::: "memory");
        } else {
            asm volatile("s_waitcnt vmcnt(0)" ::: "memory");
        }
        barrier_nodrain();
        const unsigned short* Ab = &S[cur * 8192];
        const unsigned short* Bb = &S[24576 + cur * 16384];
#pragma unroll
        for (int kk = 0; kk < 2; ++kk) {
            const int sw = ((kk * 4 + lk) ^ (lrow & 7)) * 8;
            s16x8 af[4], bf[4];
#pragma unroll
            for (int mf = 0; mf < 4; ++mf)
                af[mf] = *(const s16x8*)&Ab[(wm * 64 + mf * 16 + lrow) * 64 + sw];
#pragma unroll
            for (int nf = 0; nf < 4; ++nf)
                bf[nf] = *(const s16x8*)&Bb[(wn * 64 + nf * 16 + lrow) * 64 + sw];
            __builtin_amdgcn_s_setprio(1);
#pragma unroll
            for (int mf = 0; mf < 4; ++mf)
#pragma unroll
                for (int nf = 0; nf < 4; ++nf)
                    acc[mf][nf] = __builtin_amdgcn_mfma_f32_16x16x32_bf16(af[mf], bf[nf], acc[mf][nf], 0, 0, 0);
            __builtin_amdgcn_s_setprio(0);
        }
        barrier_nodrain();
        cur = (cur + 1 == 3) ? 0 : cur + 1;
    }

#pragma unroll
    for (int mf = 0; mf < 4; ++mf)
#pragma unroll
        for (int nf = 0; nf < 4; ++nf)
#pragma unroll
            for (int r = 0; r < 4; ++r) {
                int row = m0 + wm * 64 + mf * 16 + lk * 4 + r;
                int col = n0 + wn * 64 + nf * 16 + lrow;
                C[(long)row * DM + col] = acc[mf][nf][r];
            }
}

// ---------------- Flash attention: MFMA-ones row-sum (VGPR now slack), max3 tree ----------------
__global__ __launch_bounds__(256, 4) void attn_kernel(const unsigned short* __restrict__ Q,
                                                      const unsigned short* __restrict__ Kb,
                                                      const unsigned short* __restrict__ Vt,
                                                      unsigned short* __restrict__ O) {
    __shared__ __align__(16) unsigned short Ks[2][64 * 64];   // 16 KB
    __shared__ __align__(16) unsigned short Vs[2][64 * 64];   // 16 KB
    __shared__ __align__(16) unsigned short Pl[4][16 * 64];   //  8 KB  (total 40960 = 4 blk/CU)

    const int t = threadIdx.x;
    const int lane = t & 63, w = t >> 6;
    const int lrow = lane & 15, lk = lane >> 4;
    const int hb = blockIdx.x;
    const int h = hb & 15, b = hb >> 4;
    const int qb = 15 - blockIdx.y;                // heavy blocks dispatch first
    const int row0 = b * T_SZ;
    const int q0w = qb * 128 + w * 32;

    s16x8 qf[2][2];
#pragma unroll
    for (int hh = 0; hh < 2; ++hh) {
        const unsigned short* qp = Q + (long)(row0 + q0w + hh * 16 + lrow) * DM + h * DK + lk * 8;
        qf[hh][0] = *(const s16x8*)qp;
        qf[hh][1] = *(const s16x8*)(qp + 32);
    }

    const short onebf = (short)0x3F80;             // bf16 1.0
    const s16x8 ones = {onebf, onebf, onebf, onebf, onebf, onebf, onebf, onebf};

    fx4 acc[2][4] = {};
    fx4 suml[2] = {};                              // MFMA row-sums (denominator)
    float mrun[2] = {NINF, NINF};

    const int srow = t >> 3;                               // 0..31
    const int chk = (t & 7) ^ (srow & 7);                  // source pre-swizzle
    const unsigned short* Kg = Kb + (long)(row0 + srow) * DM + h * DK + chk * 8;
    const unsigned short* Vg = Vt + (long)(h * DK + srow) * M_SZ + row0 + chk * 8;
    unsigned short* Kl = &Ks[0][t * 8];
    unsigned short* Vl = &Vs[0][t * 8];

    const int nt = 2 * qb + 2;

    async16(Kg, Kl);
    async16(Kg + 32 * DM, Kl + 2048);
    async16(Vg, Vl);
    async16(Vg + 32 * (long)M_SZ, Vl + 2048);
    asm volatile("s_waitcnt vmcnt(0)" ::: "memory");
    __syncthreads();

    for (int kt = 0; kt < nt; ++kt) {
        const int cur = kt & 1;
        const bool pre = (kt + 1 < nt);
        if (pre) {
            const long koff = (long)(kt + 1) * 64 * DM;
            const int voff = (kt + 1) * 64;
            async16(Kg + koff, Kl + (cur ^ 1) * 4096);
            async16(Kg + koff + 32 * DM, Kl + (cur ^ 1) * 4096 + 2048);
            async16(Vg + voff, Vl + (cur ^ 1) * 4096);
            async16(Vg + voff + 32 * (long)M_SZ, Vl + (cur ^ 1) * 4096 + 2048);
        }
        const int kv0 = kt * 64;
        if (kv0 <= q0w + 31) {
            const char* ksb = (const char*)&Ks[cur][0];
            float p[2][4][4];
#pragma unroll
            for (int sub = 0; sub < 4; ++sub) {
                const int kv0s = kv0 + sub * 16;
                if (kv0s <= q0w + 31) {          // half 1 active
                    const int rb = (sub * 16 + lrow) << 7;
                    const int sw = (lrow & 7) << 4;
                    const s16x8 kf0 = *(const s16x8*)(ksb + (rb + ((lk * 16) ^ sw)));
                    const s16x8 kf1 = *(const s16x8*)(ksb + (rb + ((64 + lk * 16) ^ sw)));
                    fx4 s1 = {};
                    s1 = __builtin_amdgcn_mfma_f32_16x16x32_bf16(kf0, qf[1][0], s1, 0, 0, 0);
                    s1 = __builtin_amdgcn_mfma_f32_16x16x32_bf16(kf1, qf[1][1], s1, 0, 0, 0);
                    if (kv0s + 15 > q0w + 16) {
#pragma unroll
                        for (int r = 0; r < 4; ++r)
                            if (kv0s + lk * 4 + r > q0w + 16 + lrow) s1[r] = NINF;
                    }
#pragma unroll
                    for (int r = 0; r < 4; ++r) p[1][sub][r] = s1[r];
                    if (kv0s <= q0w + 15) {      // half 0 active
                        fx4 s0 = {};
                        s0 = __builtin_amdgcn_mfma_f32_16x16x32_bf16(kf0, qf[0][0], s0, 0, 0, 0);
                        s0 = __builtin_amdgcn_mfma_f32_16x16x32_bf16(kf1, qf[0][1], s0, 0, 0, 0);
                        if (kv0s + 15 > q0w) {
#pragma unroll
                            for (int r = 0; r < 4; ++r)
                                if (kv0s + lk * 4 + r > q0w + lrow) s0[r] = NINF;
                        }
#pragma unroll
                        for (int r = 0; r < 4; ++r) p[0][sub][r] = s0[r];
                    } else {
#pragma unroll
                        for (int r = 0; r < 4; ++r) p[0][sub][r] = NINF;
                    }
                } else {
#pragma unroll
                    for (int r = 0; r < 4; ++r) { p[0][sub][r] = NINF; p[1][sub][r] = NINF; }
                }
            }
            // ---- online softmax per half: max3 tree, branch-local shuffles ----
#pragma unroll
            for (int hh = 0; hh < 2; ++hh) {
                float t0 = MAX3(p[hh][0][0], p[hh][0][1], p[hh][0][2]);
                float t1 = MAX3(p[hh][0][3], p[hh][1][0], p[hh][1][1]);
                float t2 = MAX3(p[hh][1][2], p[hh][1][3], p[hh][2][0]);
                float t3 = MAX3(p[hh][2][1], p[hh][2][2], p[hh][2][3]);
                float t4 = MAX3(p[hh][3][0], p[hh][3][1], p[hh][3][2]);
                float pm = fmaxf(MAX3(MAX3(t0, t1, t2), t3, t4), p[hh][3][3]);
                if (__any(pm > mrun[hh] + 8.f)) {        // rare: full row-max + rescale
                    pm = fmaxf(pm, __shfl_xor(pm, 16));
                    pm = fmaxf(pm, __shfl_xor(pm, 32));
                    const float mnew = fmaxf(mrun[hh], pm);
                    const float sc = exp2f(mrun[hh] - mnew);
                    mrun[hh] = mnew;
#pragma unroll
                    for (int r = 0; r < 4; ++r) {
                        const float scr = __shfl(sc, lk * 4 + r);
                        acc[hh][0][r] *= scr; acc[hh][1][r] *= scr;
                        acc[hh][2][r] *= scr; acc[hh][3][r] *= scr;
                        suml[hh][r] *= scr;
                    }
                }
#pragma unroll
                for (int sub = 0; sub < 4; ++sub)
#pragma unroll
                    for (int r = 0; r < 4; ++r)
                        p[hh][sub][r] = exp2f(p[hh][sub][r] - mrun[hh]);
            }
            s16x8 pf[2][2];
#pragma unroll
            for (int hh = 0; hh < 2; ++hh) {
#pragma unroll
                for (int sub = 0; sub < 4; ++sub) {
                    uint2 pw;
                    pw.x = cvtpk(p[hh][sub][0], p[hh][sub][1]);
                    pw.y = cvtpk(p[hh][sub][2], p[hh][sub][3]);
                    *(uint2*)&Pl[w][lrow * 64 + ((sub * 16 + lk * 4) ^ ((lrow & 7) << 3))] = pw;
                }
                pf[hh][0] = *(const s16x8*)&Pl[w][lrow * 64 + ((lk * 8) ^ ((lrow & 7) << 3))];
                pf[hh][1] = *(const s16x8*)&Pl[w][lrow * 64 + ((32 + lk * 8) ^ ((lrow & 7) << 3))];
            }
#pragma unroll
            for (int s = 0; s < 2; ++s) {
                if (kv0 + s * 32 <= q0w + 31) {
                    const bool h0a = (kv0 + s * 32 <= q0w + 15);
                    if (h0a)
                        suml[0] = __builtin_amdgcn_mfma_f32_16x16x32_bf16(pf[0][s], ones, suml[0], 0, 0, 0);
                    suml[1] = __builtin_amdgcn_mfma_f32_16x16x32_bf16(pf[1][s], ones, suml[1], 0, 0, 0);
#pragma unroll
                    for (int nf = 0; nf < 4; ++nf) {
                        const int d = nf * 16 + lrow;
                        const s16x8 vf = *(const s16x8*)&Vs[cur][d * 64 + (((s * 4 + lk) ^ (lrow & 7)) << 3)];
                        if (h0a)
                            acc[0][nf] = __builtin_amdgcn_mfma_f32_16x16x32_bf16(pf[0][s], vf, acc[0][nf], 0, 0, 0);
                        acc[1][nf] = __builtin_amdgcn_mfma_f32_16x16x32_bf16(pf[1][s], vf, acc[1][nf], 0, 0, 0);
                    }
                }
            }
        }
        asm volatile("s_waitcnt vmcnt(0)" ::: "memory");
        __syncthreads();
    }

    // ---- epilogue: per-lane divide by MFMA row-sum (no shuffles) ----
#pragma unroll
    for (int hh = 0; hh < 2; ++hh) {
        float linv[4];
#pragma unroll
        for (int r = 0; r < 4; ++r) linv[r] = 1.f / suml[hh][r];
        unsigned short* op = O + (long)(row0 + q0w + hh * 16) * DM + h * DK;
#pragma unroll
        for (int nf = 0; nf < 4; ++nf)
#pragma unroll
            for (int r = 0; r < 4; ++r)
                op[(long)(lk * 4 + r) * DM + nf * 16 + lrow] = f2bf(acc[hh][nf][r] * linv[r]);
    }
}

extern "C" void kernel_launch(void* const* d_in, const int* in_sizes, int n_in,
                              void* d_out, int out_size, void* d_ws, size_t ws_size,
                              hipStream_t stream) {
    const float* x  = (const float*)d_in[0];
    const float* Wq = (const float*)d_in[1];
    const float* Wk = (const float*)d_in[2];
    const float* Wv = (const float*)d_in[3];
    const float* Wo = (const float*)d_in[4];
    float* out = (float*)d_out;

    unsigned short* wsu = (unsigned short*)d_ws;
    unsigned short* xb  = wsu;                  // 8,388,608 elems
    unsigned short* wqb = xb + 8388608;         // 4 x 1,048,576 (contiguous: Wq,Wk,Wv,Wo)
    unsigned short* wob = wqb + 3 * 1048576;
    unsigned short* Qs  = wob + 1048576;        // 8,388,608
    unsigned short* Ob  = Qs + 8388608;         // 8,388,608 (attn output O)

    unsigned short* Kb = (unsigned short*)d_out;        // 16MB in d_out
    unsigned short* Vt = Kb + 8388608;                  // 16MB in d_out (V transposed)

    cast_all<<<dim3(512, 5), 256, 0, stream>>>(x, Wq, Wk, Wv, Wo, xb, wqb);

    // fused Q/K/V projection as one N=3072 GEMM: 12 col-tiles x 64 row-tiles = 768 blocks
    gemm_qkv256<<<dim3(12, M_SZ / 128), 512, 0, stream>>>(xb, wqb, Qs, Kb, Vt);

    dim3 agrid(64, 16);                // x = (b,h) -> fixed XCD; y -> qb (heavy first)
    attn_kernel<<<agrid, 256, 0, stream>>>(Qs, Kb, Vt, Ob);

    // output projection with the same 3-buffer structure
    gemm_out256<<<dim3(DM / 256, M_SZ / 128), 512, 0, stream>>>(Ob, wob, out);
}

// Round 17
// 177.102 us; speedup vs baseline: 1.0189x; 1.0189x over previous
//
#include <hip/hip_runtime.h>

typedef __attribute__((ext_vector_type(8))) short s16x8;
typedef __attribute__((ext_vector_type(4))) float fx4;
typedef __attribute__((ext_vector_type(4))) int ix4;

#define B_SZ 4
#define T_SZ 2048
#define DM 1024
#define NH 16
#define DK 64
#define M_SZ (B_SZ * T_SZ)   // 8192
#define NINF (-__builtin_inff())
#define QSCALE (0.125f * 1.44269504088896340736f)
#define MAX3(a,b,c) fmaxf(fmaxf(a,b),c)

__device__ __forceinline__ unsigned short f2bf(float f) {
    unsigned int u = __float_as_uint(f);
    unsigned int r = u + 0x7fffu + ((u >> 16) & 1u);
    return (unsigned short)(r >> 16);
}

__device__ __forceinline__ unsigned cvtpk(float lo, float hi) {
    unsigned r;
    asm("v_cvt_pk_bf16_f32 %0, %1, %2" : "=v"(r) : "v"(lo), "v"(hi));
    return r;
}

__device__ __forceinline__ void async16(const unsigned short* g, unsigned short* l) {
    __builtin_amdgcn_global_load_lds(
        (const __attribute__((address_space(1))) unsigned int*)g,
        (__attribute__((address_space(3))) unsigned int*)l, 16, 0, 0);
}

// raw workgroup barrier WITHOUT the __syncthreads vmcnt(0) drain.
__device__ __forceinline__ void barrier_nodrain() {
    asm volatile("" ::: "memory");
    __builtin_amdgcn_s_barrier();
    asm volatile("" ::: "memory");
}

// ---------------- merged cast: y==0 -> x (8.4M), y==1..4 -> weights ----------------
__global__ void cast_all(const float* __restrict__ x,
                         const float* __restrict__ s1, const float* __restrict__ s2,
                         const float* __restrict__ s3, const float* __restrict__ s4,
                         unsigned short* __restrict__ xb, unsigned short* __restrict__ wb) {
    const int y = blockIdx.y;
    const float* s;
    unsigned short* d;
    int n;
    if (y == 0) { s = x; d = xb; n = M_SZ * DM; }
    else {
        s = (y == 1) ? s1 : (y == 2) ? s2 : (y == 3) ? s3 : s4;
        d = wb + (size_t)(y - 1) * (DM * DM);
        n = DM * DM;
    }
    int i = (blockIdx.x * blockDim.x + threadIdx.x) * 4;
    int stride = gridDim.x * blockDim.x * 4;
    for (; i + 3 < n; i += stride) {
        float4 v = *(const float4*)(s + i);
        ushort4 o;
        o.x = f2bf(v.x); o.y = f2bf(v.y); o.z = f2bf(v.z); o.w = f2bf(v.w);
        *(ushort4*)(d + i) = o;
    }
}

// ---------------- fused QKV GEMM: 128x256 tile, BK=64, cross-barrier 2-buffer pipeline ----------------
// stage(next) -> vmcnt(6) [prev tile's loads] -> RAW barrier -> compute -> RAW barrier.
// (R15-verified: non-attn ~95us. 3-buffer variant regressed — reverted.)
__global__ __launch_bounds__(512, 2) void gemm_qkv256(const unsigned short* __restrict__ A,
                                                      const unsigned short* __restrict__ W,
                                                      unsigned short* __restrict__ Qs,
                                                      unsigned short* __restrict__ Kb,
                                                      unsigned short* __restrict__ Vt) {
    __shared__ __align__(16) unsigned short S[49152];   // 96 KB

    const int t = threadIdx.x;
    const int lane = t & 63, w = t >> 6;
    const int wm = w >> 2, wn = w & 3;          // 2 x 4 wave grid
    const int lrow = lane & 15, lk = lane >> 4;
    const int bx = blockIdx.x;                  // 0..11
    const int m0 = blockIdx.y * 128;
    const int K = DM;
    const int NKT = K / 64;                     // 16

    fx4 acc[4][4] = {};

    const int srow = t >> 3;                    // 0..63
    const int cs = (t & 7) ^ (srow & 7);        // swizzled source chunk
    const unsigned short* Ag = A + (long)(m0 + srow) * K + cs * 8;
    const unsigned short* Bg = W + (long)(bx * 256 + srow) * K + cs * 8;

    // prologue: issue tile 0 -> buf 0 (first loop iteration waits on it)
    async16(Ag,           &S[t * 8]);
    async16(Ag + 64 * K,  &S[4096 + t * 8]);
    async16(Bg,           &S[16384 + t * 8]);
    async16(Bg + 64 * K,  &S[16384 + 4096 + t * 8]);
    async16(Bg + 128 * K, &S[16384 + 8192 + t * 8]);
    async16(Bg + 192 * K, &S[16384 + 12288 + t * 8]);

    for (int kt = 0; kt < NKT; ++kt) {
        const int cur = kt & 1;
        if (kt + 1 < NKT) {
            const int ko = (kt + 1) * 64;
            const int nbA = (cur ^ 1) * 8192;
            const int nbB = 16384 + (cur ^ 1) * 16384;
            async16(Ag + ko,           &S[nbA + t * 8]);
            async16(Ag + 64 * K + ko,  &S[nbA + 4096 + t * 8]);
            async16(Bg + ko,           &S[nbB + t * 8]);
            async16(Bg + 64 * K + ko,  &S[nbB + 4096 + t * 8]);
            async16(Bg + 128 * K + ko, &S[nbB + 8192 + t * 8]);
            async16(Bg + 192 * K + ko, &S[nbB + 12288 + t * 8]);
            asm volatile("s_waitcnt vmcnt(6)" ::: "memory");   // tile kt's 6 loads landed
        } else {
            asm volatile("s_waitcnt vmcnt(0)" ::: "memory");
        }
        barrier_nodrain();                                     // A: buf[cur] ready block-wide
        const unsigned short* Ab = &S[cur * 8192];
        const unsigned short* Bb = &S[16384 + cur * 16384];
#pragma unroll
        for (int kk = 0; kk < 2; ++kk) {
            const int sw = ((kk * 4 + lk) ^ (lrow & 7)) * 8;
            s16x8 af[4], bf[4];
#pragma unroll
            for (int mf = 0; mf < 4; ++mf)
                af[mf] = *(const s16x8*)&Ab[(wm * 64 + mf * 16 + lrow) * 64 + sw];
#pragma unroll
            for (int nf = 0; nf < 4; ++nf)
                bf[nf] = *(const s16x8*)&Bb[(wn * 64 + nf * 16 + lrow) * 64 + sw];
            __builtin_amdgcn_s_setprio(1);
#pragma unroll
            for (int mf = 0; mf < 4; ++mf)
#pragma unroll
                for (int nf = 0; nf < 4; ++nf)
                    acc[mf][nf] = __builtin_amdgcn_mfma_f32_16x16x32_bf16(af[mf], bf[nf], acc[mf][nf], 0, 0, 0);
            __builtin_amdgcn_s_setprio(0);
        }
        barrier_nodrain();                                     // B: reads of buf[cur] done
    }

    const int which = bx >> 2;
    const int n0l = (bx & 3) * 256;
    if (which < 2) {
        unsigned short* dst = which ? Kb : Qs;
        const float sc = which ? 1.f : QSCALE;
#pragma unroll
        for (int mf = 0; mf < 4; ++mf)
#pragma unroll
            for (int nf = 0; nf < 4; ++nf)
#pragma unroll
                for (int r = 0; r < 4; ++r) {
                    int row = m0 + wm * 64 + mf * 16 + lk * 4 + r;
                    int col = n0l + wn * 64 + nf * 16 + lrow;
                    dst[(long)row * DM + col] = f2bf(acc[mf][nf][r] * sc);
                }
    } else {
#pragma unroll
        for (int mf = 0; mf < 4; ++mf)
#pragma unroll
            for (int nf = 0; nf < 4; ++nf) {
                const int cl = wn * 64 + nf * 16 + lrow;
                const int rl = wm * 64 + mf * 16 + lk * 4;
                ushort4 pk;
                pk.x = f2bf(acc[mf][nf][0]); pk.y = f2bf(acc[mf][nf][1]);
                pk.z = f2bf(acc[mf][nf][2]); pk.w = f2bf(acc[mf][nf][3]);
                *(ushort4*)&S[cl * 132 + rl] = pk;
            }
        __syncthreads();
        const int c = t >> 1, h2 = t & 1;
        unsigned short* vtp = Vt + (long)(n0l + c) * M_SZ + m0 + h2 * 64;
#pragma unroll
        for (int j = 0; j < 8; ++j) {
            union { struct { ushort4 a, b; } s; ix4 v; } u;
            u.s.a = *(const ushort4*)&S[c * 132 + h2 * 64 + j * 8];
            u.s.b = *(const ushort4*)&S[c * 132 + h2 * 64 + j * 8 + 4];
            *(ix4*)(vtp + j * 8) = u.v;
        }
    }
}

// ---------------- output GEMM: same cross-barrier 2-buffer pipeline, fp32 epilogue ----------------
__global__ __launch_bounds__(512, 2) void gemm_out256(const unsigned short* __restrict__ A,
                                                      const unsigned short* __restrict__ W,
                                                      float* __restrict__ C) {
    __shared__ __align__(16) unsigned short S[49152];   // 96 KB

    const int t = threadIdx.x;
    const int lane = t & 63, w = t >> 6;
    const int wm = w >> 2, wn = w & 3;
    const int lrow = lane & 15, lk = lane >> 4;
    const int n0 = blockIdx.x * 256;
    const int m0 = blockIdx.y * 128;
    const int K = DM;
    const int NKT = K / 64;

    fx4 acc[4][4] = {};

    const int srow = t >> 3;
    const int cs = (t & 7) ^ (srow & 7);
    const unsigned short* Ag = A + (long)(m0 + srow) * K + cs * 8;
    const unsigned short* Bg = W + (long)(n0 + srow) * K + cs * 8;

    async16(Ag,           &S[t * 8]);
    async16(Ag + 64 * K,  &S[4096 + t * 8]);
    async16(Bg,           &S[16384 + t * 8]);
    async16(Bg + 64 * K,  &S[16384 + 4096 + t * 8]);
    async16(Bg + 128 * K, &S[16384 + 8192 + t * 8]);
    async16(Bg + 192 * K, &S[16384 + 12288 + t * 8]);

    for (int kt = 0; kt < NKT; ++kt) {
        const int cur = kt & 1;
        if (kt + 1 < NKT) {
            const int ko = (kt + 1) * 64;
            const int nbA = (cur ^ 1) * 8192;
            const int nbB = 16384 + (cur ^ 1) * 16384;
            async16(Ag + ko,           &S[nbA + t * 8]);
            async16(Ag + 64 * K + ko,  &S[nbA + 4096 + t * 8]);
            async16(Bg + ko,           &S[nbB + t * 8]);
            async16(Bg + 64 * K + ko,  &S[nbB + 4096 + t * 8]);
            async16(Bg + 128 * K + ko, &S[nbB + 8192 + t * 8]);
            async16(Bg + 192 * K + ko, &S[nbB + 12288 + t * 8]);
            asm volatile("s_waitcnt vmcnt(6)" ::: "memory");
        } else {
            asm volatile("s_waitcnt vmcnt(0)" ::: "memory");
        }
        barrier_nodrain();
        const unsigned short* Ab = &S[cur * 8192];
        const unsigned short* Bb = &S[16384 + cur * 16384];
#pragma unroll
        for (int kk = 0; kk < 2; ++kk) {
            const int sw = ((kk * 4 + lk) ^ (lrow & 7)) * 8;
            s16x8 af[4], bf[4];
#pragma unroll
            for (int mf = 0; mf < 4; ++mf)
                af[mf] = *(const s16x8*)&Ab[(wm * 64 + mf * 16 + lrow) * 64 + sw];
#pragma unroll
            for (int nf = 0; nf < 4; ++nf)
                bf[nf] = *(const s16x8*)&Bb[(wn * 64 + nf * 16 + lrow) * 64 + sw];
            __builtin_amdgcn_s_setprio(1);
#pragma unroll
            for (int mf = 0; mf < 4; ++mf)
#pragma unroll
                for (int nf = 0; nf < 4; ++nf)
                    acc[mf][nf] = __builtin_amdgcn_mfma_f32_16x16x32_bf16(af[mf], bf[nf], acc[mf][nf], 0, 0, 0);
            __builtin_amdgcn_s_setprio(0);
        }
        barrier_nodrain();
    }

#pragma unroll
    for (int mf = 0; mf < 4; ++mf)
#pragma unroll
        for (int nf = 0; nf < 4; ++nf)
#pragma unroll
            for (int r = 0; r < 4; ++r) {
                int row = m0 + wm * 64 + mf * 16 + lk * 4 + r;
                int col = n0 + wn * 64 + nf * 16 + lrow;
                C[(long)row * DM + col] = acc[mf][nf][r];
            }
}

// ---------------- Flash attention: MFMA-ones row-sum (R16-verified 81.3us, 64 VGPR) ----------------
__global__ __launch_bounds__(256, 4) void attn_kernel(const unsigned short* __restrict__ Q,
                                                      const unsigned short* __restrict__ Kb,
                                                      const unsigned short* __restrict__ Vt,
                                                      unsigned short* __restrict__ O) {
    __shared__ __align__(16) unsigned short Ks[2][64 * 64];   // 16 KB
    __shared__ __align__(16) unsigned short Vs[2][64 * 64];   // 16 KB
    __shared__ __align__(16) unsigned short Pl[4][16 * 64];   //  8 KB  (total 40960 = 4 blk/CU)

    const int t = threadIdx.x;
    const int lane = t & 63, w = t >> 6;
    const int lrow = lane & 15, lk = lane >> 4;
    const int hb = blockIdx.x;
    const int h = hb & 15, b = hb >> 4;
    const int qb = 15 - blockIdx.y;                // heavy blocks dispatch first
    const int row0 = b * T_SZ;
    const int q0w = qb * 128 + w * 32;

    s16x8 qf[2][2];
#pragma unroll
    for (int hh = 0; hh < 2; ++hh) {
        const unsigned short* qp = Q + (long)(row0 + q0w + hh * 16 + lrow) * DM + h * DK + lk * 8;
        qf[hh][0] = *(const s16x8*)qp;
        qf[hh][1] = *(const s16x8*)(qp + 32);
    }

    const short onebf = (short)0x3F80;             // bf16 1.0
    const s16x8 ones = {onebf, onebf, onebf, onebf, onebf, onebf, onebf, onebf};

    fx4 acc[2][4] = {};
    fx4 suml[2] = {};                              // MFMA row-sums (denominator)
    float mrun[2] = {NINF, NINF};

    const int srow = t >> 3;                               // 0..31
    const int chk = (t & 7) ^ (srow & 7);                  // source pre-swizzle
    const unsigned short* Kg = Kb + (long)(row0 + srow) * DM + h * DK + chk * 8;
    const unsigned short* Vg = Vt + (long)(h * DK + srow) * M_SZ + row0 + chk * 8;
    unsigned short* Kl = &Ks[0][t * 8];
    unsigned short* Vl = &Vs[0][t * 8];

    const int nt = 2 * qb + 2;

    async16(Kg, Kl);
    async16(Kg + 32 * DM, Kl + 2048);
    async16(Vg, Vl);
    async16(Vg + 32 * (long)M_SZ, Vl + 2048);
    asm volatile("s_waitcnt vmcnt(0)" ::: "memory");
    __syncthreads();

    for (int kt = 0; kt < nt; ++kt) {
        const int cur = kt & 1;
        const bool pre = (kt + 1 < nt);
        if (pre) {
            const long koff = (long)(kt + 1) * 64 * DM;
            const int voff = (kt + 1) * 64;
            async16(Kg + koff, Kl + (cur ^ 1) * 4096);
            async16(Kg + koff + 32 * DM, Kl + (cur ^ 1) * 4096 + 2048);
            async16(Vg + voff, Vl + (cur ^ 1) * 4096);
            async16(Vg + voff + 32 * (long)M_SZ, Vl + (cur ^ 1) * 4096 + 2048);
        }
        const int kv0 = kt * 64;
        if (kv0 <= q0w + 31) {
            const char* ksb = (const char*)&Ks[cur][0];
            float p[2][4][4];
#pragma unroll
            for (int sub = 0; sub < 4; ++sub) {
                const int kv0s = kv0 + sub * 16;
                if (kv0s <= q0w + 31) {          // half 1 active
                    const int rb = (sub * 16 + lrow) << 7;
                    const int sw = (lrow & 7) << 4;
                    const s16x8 kf0 = *(const s16x8*)(ksb + (rb + ((lk * 16) ^ sw)));
                    const s16x8 kf1 = *(const s16x8*)(ksb + (rb + ((64 + lk * 16) ^ sw)));
                    fx4 s1 = {};
                    s1 = __builtin_amdgcn_mfma_f32_16x16x32_bf16(kf0, qf[1][0], s1, 0, 0, 0);
                    s1 = __builtin_amdgcn_mfma_f32_16x16x32_bf16(kf1, qf[1][1], s1, 0, 0, 0);
                    if (kv0s + 15 > q0w + 16) {
#pragma unroll
                        for (int r = 0; r < 4; ++r)
                            if (kv0s + lk * 4 + r > q0w + 16 + lrow) s1[r] = NINF;
                    }
#pragma unroll
                    for (int r = 0; r < 4; ++r) p[1][sub][r] = s1[r];
                    if (kv0s <= q0w + 15) {      // half 0 active
                        fx4 s0 = {};
                        s0 = __builtin_amdgcn_mfma_f32_16x16x32_bf16(kf0, qf[0][0], s0, 0, 0, 0);
                        s0 = __builtin_amdgcn_mfma_f32_16x16x32_bf16(kf1, qf[0][1], s0, 0, 0, 0);
                        if (kv0s + 15 > q0w) {
#pragma unroll
                            for (int r = 0; r < 4; ++r)
                                if (kv0s + lk * 4 + r > q0w + lrow) s0[r] = NINF;
                        }
#pragma unroll
                        for (int r = 0; r < 4; ++r) p[0][sub][r] = s0[r];
                    } else {
#pragma unroll
                        for (int r = 0; r < 4; ++r) p[0][sub][r] = NINF;
                    }
                } else {
#pragma unroll
                    for (int r = 0; r < 4; ++r) { p[0][sub][r] = NINF; p[1][sub][r] = NINF; }
                }
            }
            // ---- online softmax per half: max3 tree, branch-local shuffles ----
#pragma unroll
            for (int hh = 0; hh < 2; ++hh) {
                float t0 = MAX3(p[hh][0][0], p[hh][0][1], p[hh][0][2]);
                float t1 = MAX3(p[hh][0][3], p[hh][1][0], p[hh][1][1]);
                float t2 = MAX3(p[hh][1][2], p[hh][1][3], p[hh][2][0]);
                float t3 = MAX3(p[hh][2][1], p[hh][2][2], p[hh][2][3]);
                float t4 = MAX3(p[hh][3][0], p[hh][3][1], p[hh][3][2]);
                float pm = fmaxf(MAX3(MAX3(t0, t1, t2), t3, t4), p[hh][3][3]);
                if (__any(pm > mrun[hh] + 8.f)) {        // rare: full row-max + rescale
                    pm = fmaxf(pm, __shfl_xor(pm, 16));
                    pm = fmaxf(pm, __shfl_xor(pm, 32));
                    const float mnew = fmaxf(mrun[hh], pm);
                    const float sc = exp2f(mrun[hh] - mnew);
                    mrun[hh] = mnew;
#pragma unroll
                    for (int r = 0; r < 4; ++r) {
                        const float scr = __shfl(sc, lk * 4 + r);
                        acc[hh][0][r] *= scr; acc[hh][1][r] *= scr;
                        acc[hh][2][r] *= scr; acc[hh][3][r] *= scr;
                        suml[hh][r] *= scr;
                    }
                }
#pragma unroll
                for (int sub = 0; sub < 4; ++sub)
#pragma unroll
                    for (int r = 0; r < 4; ++r)
                        p[hh][sub][r] = exp2f(p[hh][sub][r] - mrun[hh]);
            }
            s16x8 pf[2][2];
#pragma unroll
            for (int hh = 0; hh < 2; ++hh) {
#pragma unroll
                for (int sub = 0; sub < 4; ++sub) {
                    uint2 pw;
                    pw.x = cvtpk(p[hh][sub][0], p[hh][sub][1]);
                    pw.y = cvtpk(p[hh][sub][2], p[hh][sub][3]);
                    *(uint2*)&Pl[w][lrow * 64 + ((sub * 16 + lk * 4) ^ ((lrow & 7) << 3))] = pw;
                }
                pf[hh][0] = *(const s16x8*)&Pl[w][lrow * 64 + ((lk * 8) ^ ((lrow & 7) << 3))];
                pf[hh][1] = *(const s16x8*)&Pl[w][lrow * 64 + ((32 + lk * 8) ^ ((lrow & 7) << 3))];
            }
#pragma unroll
            for (int s = 0; s < 2; ++s) {
                if (kv0 + s * 32 <= q0w + 31) {
                    const bool h0a = (kv0 + s * 32 <= q0w + 15);
                    if (h0a)
                        suml[0] = __builtin_amdgcn_mfma_f32_16x16x32_bf16(pf[0][s], ones, suml[0], 0, 0, 0);
                    suml[1] = __builtin_amdgcn_mfma_f32_16x16x32_bf16(pf[1][s], ones, suml[1], 0, 0, 0);
#pragma unroll
                    for (int nf = 0; nf < 4; ++nf) {
                        const int d = nf * 16 + lrow;
                        const s16x8 vf = *(const s16x8*)&Vs[cur][d * 64 + (((s * 4 + lk) ^ (lrow & 7)) << 3)];
                        if (h0a)
                            acc[0][nf] = __builtin_amdgcn_mfma_f32_16x16x32_bf16(pf[0][s], vf, acc[0][nf], 0, 0, 0);
                        acc[1][nf] = __builtin_amdgcn_mfma_f32_16x16x32_bf16(pf[1][s], vf, acc[1][nf], 0, 0, 0);
                    }
                }
            }
        }
        asm volatile("s_waitcnt vmcnt(0)" ::: "memory");
        __syncthreads();
    }

    // ---- epilogue: per-lane divide by MFMA row-sum (no shuffles) ----
#pragma unroll
    for (int hh = 0; hh < 2; ++hh) {
        float linv[4];
#pragma unroll
        for (int r = 0; r < 4; ++r) linv[r] = 1.f / suml[hh][r];
        unsigned short* op = O + (long)(row0 + q0w + hh * 16) * DM + h * DK;
#pragma unroll
        for (int nf = 0; nf < 4; ++nf)
#pragma unroll
            for (int r = 0; r < 4; ++r)
                op[(long)(lk * 4 + r) * DM + nf * 16 + lrow] = f2bf(acc[hh][nf][r] * linv[r]);
    }
}

extern "C" void kernel_launch(void* const* d_in, const int* in_sizes, int n_in,
                              void* d_out, int out_size, void* d_ws, size_t ws_size,
                              hipStream_t stream) {
    const float* x  = (const float*)d_in[0];
    const float* Wq = (const float*)d_in[1];
    const float* Wk = (const float*)d_in[2];
    const float* Wv = (const float*)d_in[3];
    const float* Wo = (const float*)d_in[4];
    float* out = (float*)d_out;

    unsigned short* wsu = (unsigned short*)d_ws;
    unsigned short* xb  = wsu;                  // 8,388,608 elems
    unsigned short* wqb = xb + 8388608;         // 4 x 1,048,576 (contiguous: Wq,Wk,Wv,Wo)
    unsigned short* wob = wqb + 3 * 1048576;
    unsigned short* Qs  = wob + 1048576;        // 8,388,608
    unsigned short* Ob  = Qs + 8388608;         // 8,388,608 (attn output O)

    unsigned short* Kb = (unsigned short*)d_out;        // 16MB in d_out
    unsigned short* Vt = Kb + 8388608;                  // 16MB in d_out (V transposed)

    cast_all<<<dim3(512, 5), 256, 0, stream>>>(x, Wq, Wk, Wv, Wo, xb, wqb);

    // fused Q/K/V projection as one N=3072 GEMM: 12 col-tiles x 64 row-tiles = 768 blocks
    gemm_qkv256<<<dim3(12, M_SZ / 128), 512, 0, stream>>>(xb, wqb, Qs, Kb, Vt);

    dim3 agrid(64, 16);                // x = (b,h) -> fixed XCD; y -> qb (heavy first)
    attn_kernel<<<agrid, 256, 0, stream>>>(Qs, Kb, Vt, Ob);

    // output projection with the same 2-buffer structure
    gemm_out256<<<dim3(DM / 256, M_SZ / 128), 512, 0, stream>>>(Ob, wob, out);
}

// Round 18
// 175.451 us; speedup vs baseline: 1.0285x; 1.0094x over previous
//
#include <hip/hip_runtime.h>

typedef __attribute__((ext_vector_type(8))) short s16x8;
typedef __attribute__((ext_vector_type(4))) float fx4;
typedef __attribute__((ext_vector_type(4))) int ix4;

#define B_SZ 4
#define T_SZ 2048
#define DM 1024
#define NH 16
#define DK 64
#define M_SZ (B_SZ * T_SZ)   // 8192
#define NINF (-__builtin_inff())
#define QSCALE (0.125f * 1.44269504088896340736f)
#define MAX3(a,b,c) fmaxf(fmaxf(a,b),c)

__device__ __forceinline__ unsigned short f2bf(float f) {
    unsigned int u = __float_as_uint(f);
    unsigned int r = u + 0x7fffu + ((u >> 16) & 1u);
    return (unsigned short)(r >> 16);
}

__device__ __forceinline__ unsigned cvtpk(float lo, float hi) {
    unsigned r;
    asm("v_cvt_pk_bf16_f32 %0, %1, %2" : "=v"(r) : "v"(lo), "v"(hi));
    return r;
}

__device__ __forceinline__ void async16(const unsigned short* g, unsigned short* l) {
    __builtin_amdgcn_global_load_lds(
        (const __attribute__((address_space(1))) unsigned int*)g,
        (__attribute__((address_space(3))) unsigned int*)l, 16, 0, 0);
}

// raw workgroup barrier WITHOUT the __syncthreads vmcnt(0) drain.
__device__ __forceinline__ void barrier_nodrain() {
    asm volatile("" ::: "memory");
    __builtin_amdgcn_s_barrier();
    asm volatile("" ::: "memory");
}

// ---------------- merged cast: y==0 -> x (8.4M), y==1..4 -> weights ----------------
__global__ void cast_all(const float* __restrict__ x,
                         const float* __restrict__ s1, const float* __restrict__ s2,
                         const float* __restrict__ s3, const float* __restrict__ s4,
                         unsigned short* __restrict__ xb, unsigned short* __restrict__ wb) {
    const int y = blockIdx.y;
    const float* s;
    unsigned short* d;
    int n;
    if (y == 0) { s = x; d = xb; n = M_SZ * DM; }
    else {
        s = (y == 1) ? s1 : (y == 2) ? s2 : (y == 3) ? s3 : s4;
        d = wb + (size_t)(y - 1) * (DM * DM);
        n = DM * DM;
    }
    int i = (blockIdx.x * blockDim.x + threadIdx.x) * 4;
    int stride = gridDim.x * blockDim.x * 4;
    for (; i + 3 < n; i += stride) {
        float4 v = *(const float4*)(s + i);
        ushort4 o;
        o.x = f2bf(v.x); o.y = f2bf(v.y); o.z = f2bf(v.z); o.w = f2bf(v.w);
        *(ushort4*)(d + i) = o;
    }
}

// ---------------- fused QKV GEMM: 128x256 tile, BK=64, cross-barrier 2-buffer pipeline ----------------
// Grid (64, 12): m-tile on blockIdx.x  ->  bid%8 = mx%8  ->  all 12 consumers of an
// A-panel land on ONE XCD (A-panel L2-resident; 8 panels/XCD = 2MB of 4MB L2).
__global__ __launch_bounds__(512, 2) void gemm_qkv256(const unsigned short* __restrict__ A,
                                                      const unsigned short* __restrict__ W,
                                                      unsigned short* __restrict__ Qs,
                                                      unsigned short* __restrict__ Kb,
                                                      unsigned short* __restrict__ Vt) {
    __shared__ __align__(16) unsigned short S[49152];   // 96 KB

    const int t = threadIdx.x;
    const int lane = t & 63, w = t >> 6;
    const int wm = w >> 2, wn = w & 3;          // 2 x 4 wave grid
    const int lrow = lane & 15, lk = lane >> 4;
    const int bx = blockIdx.y;                  // 0..11 (which*4 + n-col tile)
    const int m0 = blockIdx.x * 128;
    const int K = DM;
    const int NKT = K / 64;                     // 16

    fx4 acc[4][4] = {};

    const int srow = t >> 3;                    // 0..63
    const int cs = (t & 7) ^ (srow & 7);        // swizzled source chunk
    const unsigned short* Ag = A + (long)(m0 + srow) * K + cs * 8;
    const unsigned short* Bg = W + (long)(bx * 256 + srow) * K + cs * 8;

    // prologue: issue tile 0 -> buf 0 (first loop iteration waits on it)
    async16(Ag,           &S[t * 8]);
    async16(Ag + 64 * K,  &S[4096 + t * 8]);
    async16(Bg,           &S[16384 + t * 8]);
    async16(Bg + 64 * K,  &S[16384 + 4096 + t * 8]);
    async16(Bg + 128 * K, &S[16384 + 8192 + t * 8]);
    async16(Bg + 192 * K, &S[16384 + 12288 + t * 8]);

    for (int kt = 0; kt < NKT; ++kt) {
        const int cur = kt & 1;
        if (kt + 1 < NKT) {
            const int ko = (kt + 1) * 64;
            const int nbA = (cur ^ 1) * 8192;
            const int nbB = 16384 + (cur ^ 1) * 16384;
            async16(Ag + ko,           &S[nbA + t * 8]);
            async16(Ag + 64 * K + ko,  &S[nbA + 4096 + t * 8]);
            async16(Bg + ko,           &S[nbB + t * 8]);
            async16(Bg + 64 * K + ko,  &S[nbB + 4096 + t * 8]);
            async16(Bg + 128 * K + ko, &S[nbB + 8192 + t * 8]);
            async16(Bg + 192 * K + ko, &S[nbB + 12288 + t * 8]);
            asm volatile("s_waitcnt vmcnt(6)" ::: "memory");   // tile kt's 6 loads landed
        } else {
            asm volatile("s_waitcnt vmcnt(0)" ::: "memory");
        }
        barrier_nodrain();                                     // A: buf[cur] ready block-wide
        const unsigned short* Ab = &S[cur * 8192];
        const unsigned short* Bb = &S[16384 + cur * 16384];
#pragma unroll
        for (int kk = 0; kk < 2; ++kk) {
            const int sw = ((kk * 4 + lk) ^ (lrow & 7)) * 8;
            s16x8 af[4], bf[4];
#pragma unroll
            for (int mf = 0; mf < 4; ++mf)
                af[mf] = *(const s16x8*)&Ab[(wm * 64 + mf * 16 + lrow) * 64 + sw];
#pragma unroll
            for (int nf = 0; nf < 4; ++nf)
                bf[nf] = *(const s16x8*)&Bb[(wn * 64 + nf * 16 + lrow) * 64 + sw];
            __builtin_amdgcn_s_setprio(1);
#pragma unroll
            for (int mf = 0; mf < 4; ++mf)
#pragma unroll
                for (int nf = 0; nf < 4; ++nf)
                    acc[mf][nf] = __builtin_amdgcn_mfma_f32_16x16x32_bf16(af[mf], bf[nf], acc[mf][nf], 0, 0, 0);
            __builtin_amdgcn_s_setprio(0);
        }
        barrier_nodrain();                                     // B: reads of buf[cur] done
    }

    const int which = bx >> 2;
    const int n0l = (bx & 3) * 256;
    if (which < 2) {
        unsigned short* dst = which ? Kb : Qs;
        const float sc = which ? 1.f : QSCALE;
#pragma unroll
        for (int mf = 0; mf < 4; ++mf)
#pragma unroll
            for (int nf = 0; nf < 4; ++nf)
#pragma unroll
                for (int r = 0; r < 4; ++r) {
                    int row = m0 + wm * 64 + mf * 16 + lk * 4 + r;
                    int col = n0l + wn * 64 + nf * 16 + lrow;
                    dst[(long)row * DM + col] = f2bf(acc[mf][nf][r] * sc);
                }
    } else {
#pragma unroll
        for (int mf = 0; mf < 4; ++mf)
#pragma unroll
            for (int nf = 0; nf < 4; ++nf) {
                const int cl = wn * 64 + nf * 16 + lrow;
                const int rl = wm * 64 + mf * 16 + lk * 4;
                ushort4 pk;
                pk.x = f2bf(acc[mf][nf][0]); pk.y = f2bf(acc[mf][nf][1]);
                pk.z = f2bf(acc[mf][nf][2]); pk.w = f2bf(acc[mf][nf][3]);
                *(ushort4*)&S[cl * 132 + rl] = pk;
            }
        __syncthreads();
        const int c = t >> 1, h2 = t & 1;
        unsigned short* vtp = Vt + (long)(n0l + c) * M_SZ + m0 + h2 * 64;
#pragma unroll
        for (int j = 0; j < 8; ++j) {
            union { struct { ushort4 a, b; } s; ix4 v; } u;
            u.s.a = *(const ushort4*)&S[c * 132 + h2 * 64 + j * 8];
            u.s.b = *(const ushort4*)&S[c * 132 + h2 * 64 + j * 8 + 4];
            *(ix4*)(vtp + j * 8) = u.v;
        }
    }
}

// ---------------- output GEMM: grid (64, 4) — same-XCD A-panel reuse ----------------
__global__ __launch_bounds__(512, 2) void gemm_out256(const unsigned short* __restrict__ A,
                                                      const unsigned short* __restrict__ W,
                                                      float* __restrict__ C) {
    __shared__ __align__(16) unsigned short S[49152];   // 96 KB

    const int t = threadIdx.x;
    const int lane = t & 63, w = t >> 6;
    const int wm = w >> 2, wn = w & 3;
    const int lrow = lane & 15, lk = lane >> 4;
    const int n0 = blockIdx.y * 256;
    const int m0 = blockIdx.x * 128;
    const int K = DM;
    const int NKT = K / 64;

    fx4 acc[4][4] = {};

    const int srow = t >> 3;
    const int cs = (t & 7) ^ (srow & 7);
    const unsigned short* Ag = A + (long)(m0 + srow) * K + cs * 8;
    const unsigned short* Bg = W + (long)(n0 + srow) * K + cs * 8;

    async16(Ag,           &S[t * 8]);
    async16(Ag + 64 * K,  &S[4096 + t * 8]);
    async16(Bg,           &S[16384 + t * 8]);
    async16(Bg + 64 * K,  &S[16384 + 4096 + t * 8]);
    async16(Bg + 128 * K, &S[16384 + 8192 + t * 8]);
    async16(Bg + 192 * K, &S[16384 + 12288 + t * 8]);

    for (int kt = 0; kt < NKT; ++kt) {
        const int cur = kt & 1;
        if (kt + 1 < NKT) {
            const int ko = (kt + 1) * 64;
            const int nbA = (cur ^ 1) * 8192;
            const int nbB = 16384 + (cur ^ 1) * 16384;
            async16(Ag + ko,           &S[nbA + t * 8]);
            async16(Ag + 64 * K + ko,  &S[nbA + 4096 + t * 8]);
            async16(Bg + ko,           &S[nbB + t * 8]);
            async16(Bg + 64 * K + ko,  &S[nbB + 4096 + t * 8]);
            async16(Bg + 128 * K + ko, &S[nbB + 8192 + t * 8]);
            async16(Bg + 192 * K + ko, &S[nbB + 12288 + t * 8]);
            asm volatile("s_waitcnt vmcnt(6)" ::: "memory");
        } else {
            asm volatile("s_waitcnt vmcnt(0)" ::: "memory");
        }
        barrier_nodrain();
        const unsigned short* Ab = &S[cur * 8192];
        const unsigned short* Bb = &S[16384 + cur * 16384];
#pragma unroll
        for (int kk = 0; kk < 2; ++kk) {
            const int sw = ((kk * 4 + lk) ^ (lrow & 7)) * 8;
            s16x8 af[4], bf[4];
#pragma unroll
            for (int mf = 0; mf < 4; ++mf)
                af[mf] = *(const s16x8*)&Ab[(wm * 64 + mf * 16 + lrow) * 64 + sw];
#pragma unroll
            for (int nf = 0; nf < 4; ++nf)
                bf[nf] = *(const s16x8*)&Bb[(wn * 64 + nf * 16 + lrow) * 64 + sw];
            __builtin_amdgcn_s_setprio(1);
#pragma unroll
            for (int mf = 0; mf < 4; ++mf)
#pragma unroll
                for (int nf = 0; nf < 4; ++nf)
                    acc[mf][nf] = __builtin_amdgcn_mfma_f32_16x16x32_bf16(af[mf], bf[nf], acc[mf][nf], 0, 0, 0);
            __builtin_amdgcn_s_setprio(0);
        }
        barrier_nodrain();
    }

#pragma unroll
    for (int mf = 0; mf < 4; ++mf)
#pragma unroll
        for (int nf = 0; nf < 4; ++nf)
#pragma unroll
            for (int r = 0; r < 4; ++r) {
                int row = m0 + wm * 64 + mf * 16 + lk * 4 + r;
                int col = n0 + wn * 64 + nf * 16 + lrow;
                C[(long)row * DM + col] = acc[mf][nf][r];
            }
}

// ---------------- Flash attention: MFMA-ones row-sum + setprio around MFMA clusters ----------------
__global__ __launch_bounds__(256, 4) void attn_kernel(const unsigned short* __restrict__ Q,
                                                      const unsigned short* __restrict__ Kb,
                                                      const unsigned short* __restrict__ Vt,
                                                      unsigned short* __restrict__ O) {
    __shared__ __align__(16) unsigned short Ks[2][64 * 64];   // 16 KB
    __shared__ __align__(16) unsigned short Vs[2][64 * 64];   // 16 KB
    __shared__ __align__(16) unsigned short Pl[4][16 * 64];   //  8 KB  (total 40960 = 4 blk/CU)

    const int t = threadIdx.x;
    const int lane = t & 63, w = t >> 6;
    const int lrow = lane & 15, lk = lane >> 4;
    const int hb = blockIdx.x;
    const int h = hb & 15, b = hb >> 4;
    const int qb = 15 - blockIdx.y;                // heavy blocks dispatch first
    const int row0 = b * T_SZ;
    const int q0w = qb * 128 + w * 32;

    s16x8 qf[2][2];
#pragma unroll
    for (int hh = 0; hh < 2; ++hh) {
        const unsigned short* qp = Q + (long)(row0 + q0w + hh * 16 + lrow) * DM + h * DK + lk * 8;
        qf[hh][0] = *(const s16x8*)qp;
        qf[hh][1] = *(const s16x8*)(qp + 32);
    }

    const short onebf = (short)0x3F80;             // bf16 1.0
    const s16x8 ones = {onebf, onebf, onebf, onebf, onebf, onebf, onebf, onebf};

    fx4 acc[2][4] = {};
    fx4 suml[2] = {};                              // MFMA row-sums (denominator)
    float mrun[2] = {NINF, NINF};

    const int srow = t >> 3;                               // 0..31
    const int chk = (t & 7) ^ (srow & 7);                  // source pre-swizzle
    const unsigned short* Kg = Kb + (long)(row0 + srow) * DM + h * DK + chk * 8;
    const unsigned short* Vg = Vt + (long)(h * DK + srow) * M_SZ + row0 + chk * 8;
    unsigned short* Kl = &Ks[0][t * 8];
    unsigned short* Vl = &Vs[0][t * 8];

    const int nt = 2 * qb + 2;

    async16(Kg, Kl);
    async16(Kg + 32 * DM, Kl + 2048);
    async16(Vg, Vl);
    async16(Vg + 32 * (long)M_SZ, Vl + 2048);
    asm volatile("s_waitcnt vmcnt(0)" ::: "memory");
    __syncthreads();

    for (int kt = 0; kt < nt; ++kt) {
        const int cur = kt & 1;
        const bool pre = (kt + 1 < nt);
        if (pre) {
            const long koff = (long)(kt + 1) * 64 * DM;
            const int voff = (kt + 1) * 64;
            async16(Kg + koff, Kl + (cur ^ 1) * 4096);
            async16(Kg + koff + 32 * DM, Kl + (cur ^ 1) * 4096 + 2048);
            async16(Vg + voff, Vl + (cur ^ 1) * 4096);
            async16(Vg + voff + 32 * (long)M_SZ, Vl + (cur ^ 1) * 4096 + 2048);
        }
        const int kv0 = kt * 64;
        if (kv0 <= q0w + 31) {
            const char* ksb = (const char*)&Ks[cur][0];
            float p[2][4][4];
#pragma unroll
            for (int sub = 0; sub < 4; ++sub) {
                const int kv0s = kv0 + sub * 16;
                if (kv0s <= q0w + 31) {          // half 1 active
                    const int rb = (sub * 16 + lrow) << 7;
                    const int sw = (lrow & 7) << 4;
                    const s16x8 kf0 = *(const s16x8*)(ksb + (rb + ((lk * 16) ^ sw)));
                    const s16x8 kf1 = *(const s16x8*)(ksb + (rb + ((64 + lk * 16) ^ sw)));
                    __builtin_amdgcn_s_setprio(1);
                    fx4 s1 = {};
                    s1 = __builtin_amdgcn_mfma_f32_16x16x32_bf16(kf0, qf[1][0], s1, 0, 0, 0);
                    s1 = __builtin_amdgcn_mfma_f32_16x16x32_bf16(kf1, qf[1][1], s1, 0, 0, 0);
                    __builtin_amdgcn_s_setprio(0);
                    if (kv0s + 15 > q0w + 16) {
#pragma unroll
                        for (int r = 0; r < 4; ++r)
                            if (kv0s + lk * 4 + r > q0w + 16 + lrow) s1[r] = NINF;
                    }
#pragma unroll
                    for (int r = 0; r < 4; ++r) p[1][sub][r] = s1[r];
                    if (kv0s <= q0w + 15) {      // half 0 active
                        __builtin_amdgcn_s_setprio(1);
                        fx4 s0 = {};
                        s0 = __builtin_amdgcn_mfma_f32_16x16x32_bf16(kf0, qf[0][0], s0, 0, 0, 0);
                        s0 = __builtin_amdgcn_mfma_f32_16x16x32_bf16(kf1, qf[0][1], s0, 0, 0, 0);
                        __builtin_amdgcn_s_setprio(0);
                        if (kv0s + 15 > q0w) {
#pragma unroll
                            for (int r = 0; r < 4; ++r)
                                if (kv0s + lk * 4 + r > q0w + lrow) s0[r] = NINF;
                        }
#pragma unroll
                        for (int r = 0; r < 4; ++r) p[0][sub][r] = s0[r];
                    } else {
#pragma unroll
                        for (int r = 0; r < 4; ++r) p[0][sub][r] = NINF;
                    }
                } else {
#pragma unroll
                    for (int r = 0; r < 4; ++r) { p[0][sub][r] = NINF; p[1][sub][r] = NINF; }
                }
            }
            // ---- online softmax per half: max3 tree, branch-local shuffles ----
#pragma unroll
            for (int hh = 0; hh < 2; ++hh) {
                float t0 = MAX3(p[hh][0][0], p[hh][0][1], p[hh][0][2]);
                float t1 = MAX3(p[hh][0][3], p[hh][1][0], p[hh][1][1]);
                float t2 = MAX3(p[hh][1][2], p[hh][1][3], p[hh][2][0]);
                float t3 = MAX3(p[hh][2][1], p[hh][2][2], p[hh][2][3]);
                float t4 = MAX3(p[hh][3][0], p[hh][3][1], p[hh][3][2]);
                float pm = fmaxf(MAX3(MAX3(t0, t1, t2), t3, t4), p[hh][3][3]);
                if (__any(pm > mrun[hh] + 8.f)) {        // rare: full row-max + rescale
                    pm = fmaxf(pm, __shfl_xor(pm, 16));
                    pm = fmaxf(pm, __shfl_xor(pm, 32));
                    const float mnew = fmaxf(mrun[hh], pm);
                    const float sc = exp2f(mrun[hh] - mnew);
                    mrun[hh] = mnew;
#pragma unroll
                    for (int r = 0; r < 4; ++r) {
                        const float scr = __shfl(sc, lk * 4 + r);
                        acc[hh][0][r] *= scr; acc[hh][1][r] *= scr;
                        acc[hh][2][r] *= scr; acc[hh][3][r] *= scr;
                        suml[hh][r] *= scr;
                    }
                }
#pragma unroll
                for (int sub = 0; sub < 4; ++sub)
#pragma unroll
                    for (int r = 0; r < 4; ++r)
                        p[hh][sub][r] = exp2f(p[hh][sub][r] - mrun[hh]);
            }
            s16x8 pf[2][2];
#pragma unroll
            for (int hh = 0; hh < 2; ++hh) {
#pragma unroll
                for (int sub = 0; sub < 4; ++sub) {
                    uint2 pw;
                    pw.x = cvtpk(p[hh][sub][0], p[hh][sub][1]);
                    pw.y = cvtpk(p[hh][sub][2], p[hh][sub][3]);
                    *(uint2*)&Pl[w][lrow * 64 + ((sub * 16 + lk * 4) ^ ((lrow & 7) << 3))] = pw;
                }
                pf[hh][0] = *(const s16x8*)&Pl[w][lrow * 64 + ((lk * 8) ^ ((lrow & 7) << 3))];
                pf[hh][1] = *(const s16x8*)&Pl[w][lrow * 64 + ((32 + lk * 8) ^ ((lrow & 7) << 3))];
            }
#pragma unroll
            for (int s = 0; s < 2; ++s) {
                if (kv0 + s * 32 <= q0w + 31) {
                    const bool h0a = (kv0 + s * 32 <= q0w + 15);
                    __builtin_amdgcn_s_setprio(1);
                    if (h0a)
                        suml[0] = __builtin_amdgcn_mfma_f32_16x16x32_bf16(pf[0][s], ones, suml[0], 0, 0, 0);
                    suml[1] = __builtin_amdgcn_mfma_f32_16x16x32_bf16(pf[1][s], ones, suml[1], 0, 0, 0);
#pragma unroll
                    for (int nf = 0; nf < 4; ++nf) {
                        const int d = nf * 16 + lrow;
                        const s16x8 vf = *(const s16x8*)&Vs[cur][d * 64 + (((s * 4 + lk) ^ (lrow & 7)) << 3)];
                        if (h0a)
                            acc[0][nf] = __builtin_amdgcn_mfma_f32_16x16x32_bf16(pf[0][s], vf, acc[0][nf], 0, 0, 0);
                        acc[1][nf] = __builtin_amdgcn_mfma_f32_16x16x32_bf16(pf[1][s], vf, acc[1][nf], 0, 0, 0);
                    }
                    __builtin_amdgcn_s_setprio(0);
                }
            }
        }
        asm volatile("s_waitcnt vmcnt(0)" ::: "memory");
        __syncthreads();
    }

    // ---- epilogue: per-lane divide by MFMA row-sum (no shuffles) ----
#pragma unroll
    for (int hh = 0; hh < 2; ++hh) {
        float linv[4];
#pragma unroll
        for (int r = 0; r < 4; ++r) linv[r] = 1.f / suml[hh][r];
        unsigned short* op = O + (long)(row0 + q0w + hh * 16) * DM + h * DK;
#pragma unroll
        for (int nf = 0; nf < 4; ++nf)
#pragma unroll
            for (int r = 0; r < 4; ++r)
                op[(long)(lk * 4 + r) * DM + nf * 16 + lrow] = f2bf(acc[hh][nf][r] * linv[r]);
    }
}

extern "C" void kernel_launch(void* const* d_in, const int* in_sizes, int n_in,
                              void* d_out, int out_size, void* d_ws, size_t ws_size,
                              hipStream_t stream) {
    const float* x  = (const float*)d_in[0];
    const float* Wq = (const float*)d_in[1];
    const float* Wk = (const float*)d_in[2];
    const float* Wv = (const float*)d_in[3];
    const float* Wo = (const float*)d_in[4];
    float* out = (float*)d_out;

    unsigned short* wsu = (unsigned short*)d_ws;
    unsigned short* xb  = wsu;                  // 8,388,608 elems
    unsigned short* wqb = xb + 8388608;         // 4 x 1,048,576 (contiguous: Wq,Wk,Wv,Wo)
    unsigned short* wob = wqb + 3 * 1048576;
    unsigned short* Qs  = wob + 1048576;        // 8,388,608
    unsigned short* Ob  = Qs + 8388608;         // 8,388,608 (attn output O)

    unsigned short* Kb = (unsigned short*)d_out;        // 16MB in d_out
    unsigned short* Vt = Kb + 8388608;                  // 16MB in d_out (V transposed)

    cast_all<<<dim3(512, 5), 256, 0, stream>>>(x, Wq, Wk, Wv, Wo, xb, wqb);

    // fused Q/K/V projection: m-tiles on x (same-XCD A-panel reuse), 12 col/which tiles on y
    gemm_qkv256<<<dim3(M_SZ / 128, 12), 512, 0, stream>>>(xb, wqb, Qs, Kb, Vt);

    dim3 agrid(64, 16);                // x = (b,h) -> fixed XCD; y -> qb (heavy first)
    attn_kernel<<<agrid, 256, 0, stream>>>(Qs, Kb, Vt, Ob);

    // output projection: m-tiles on x
    gemm_out256<<<dim3(M_SZ / 128, DM / 256), 512, 0, stream>>>(Ob, wob, out);
}

// Round 19
// 172.308 us; speedup vs baseline: 1.0473x; 1.0182x over previous
//
#include <hip/hip_runtime.h>

typedef __attribute__((ext_vector_type(8))) short s16x8;
typedef __attribute__((ext_vector_type(4))) float fx4;
typedef __attribute__((ext_vector_type(4))) int ix4;

#define B_SZ 4
#define T_SZ 2048
#define DM 1024
#define NH 16
#define DK 64
#define M_SZ (B_SZ * T_SZ)   // 8192
#define NINF (-__builtin_inff())
#define QSCALE (0.125f * 1.44269504088896340736f)
#define MAX3(a,b,c) fmaxf(fmaxf(a,b),c)

__device__ __forceinline__ unsigned short f2bf(float f) {
    unsigned int u = __float_as_uint(f);
    unsigned int r = u + 0x7fffu + ((u >> 16) & 1u);
    return (unsigned short)(r >> 16);
}

__device__ __forceinline__ unsigned cvtpk(float lo, float hi) {
    unsigned r;
    asm("v_cvt_pk_bf16_f32 %0, %1, %2" : "=v"(r) : "v"(lo), "v"(hi));
    return r;
}

__device__ __forceinline__ void async16(const unsigned short* g, unsigned short* l) {
    __builtin_amdgcn_global_load_lds(
        (const __attribute__((address_space(1))) unsigned int*)g,
        (__attribute__((address_space(3))) unsigned int*)l, 16, 0, 0);
}

// raw workgroup barrier WITHOUT the __syncthreads vmcnt(0) drain.
__device__ __forceinline__ void barrier_nodrain() {
    asm volatile("" ::: "memory");
    __builtin_amdgcn_s_barrier();
    asm volatile("" ::: "memory");
}

// ---------------- merged cast: y==0 -> x (8.4M), y==1..4 -> weights ----------------
__global__ void cast_all(const float* __restrict__ x,
                         const float* __restrict__ s1, const float* __restrict__ s2,
                         const float* __restrict__ s3, const float* __restrict__ s4,
                         unsigned short* __restrict__ xb, unsigned short* __restrict__ wb) {
    const int y = blockIdx.y;
    const float* s;
    unsigned short* d;
    int n;
    if (y == 0) { s = x; d = xb; n = M_SZ * DM; }
    else {
        s = (y == 1) ? s1 : (y == 2) ? s2 : (y == 3) ? s3 : s4;
        d = wb + (size_t)(y - 1) * (DM * DM);
        n = DM * DM;
    }
    int i = (blockIdx.x * blockDim.x + threadIdx.x) * 4;
    int stride = gridDim.x * blockDim.x * 4;
    for (; i + 3 < n; i += stride) {
        float4 v = *(const float4*)(s + i);
        ushort4 o;
        o.x = f2bf(v.x); o.y = f2bf(v.y); o.z = f2bf(v.z); o.w = f2bf(v.w);
        *(ushort4*)(d + i) = o;
    }
}

// ---------------- fused QKV GEMM: 128x256 tile, BK=64, cross-barrier 2-buffer pipeline ----------------
// Grid (64, 12): m-tile on blockIdx.x -> all 12 consumers of an A-panel on ONE XCD.
__global__ __launch_bounds__(512, 2) void gemm_qkv256(const unsigned short* __restrict__ A,
                                                      const unsigned short* __restrict__ W,
                                                      unsigned short* __restrict__ Qs,
                                                      unsigned short* __restrict__ Kb,
                                                      unsigned short* __restrict__ Vt) {
    __shared__ __align__(16) unsigned short S[49152];   // 96 KB

    const int t = threadIdx.x;
    const int lane = t & 63, w = t >> 6;
    const int wm = w >> 2, wn = w & 3;          // 2 x 4 wave grid
    const int lrow = lane & 15, lk = lane >> 4;
    const int bx = blockIdx.y;                  // 0..11 (which*4 + n-col tile)
    const int m0 = blockIdx.x * 128;
    const int K = DM;
    const int NKT = K / 64;                     // 16

    fx4 acc[4][4] = {};

    const int srow = t >> 3;                    // 0..63
    const int cs = (t & 7) ^ (srow & 7);        // swizzled source chunk
    const unsigned short* Ag = A + (long)(m0 + srow) * K + cs * 8;
    const unsigned short* Bg = W + (long)(bx * 256 + srow) * K + cs * 8;

    async16(Ag,           &S[t * 8]);
    async16(Ag + 64 * K,  &S[4096 + t * 8]);
    async16(Bg,           &S[16384 + t * 8]);
    async16(Bg + 64 * K,  &S[16384 + 4096 + t * 8]);
    async16(Bg + 128 * K, &S[16384 + 8192 + t * 8]);
    async16(Bg + 192 * K, &S[16384 + 12288 + t * 8]);

    for (int kt = 0; kt < NKT; ++kt) {
        const int cur = kt & 1;
        if (kt + 1 < NKT) {
            const int ko = (kt + 1) * 64;
            const int nbA = (cur ^ 1) * 8192;
            const int nbB = 16384 + (cur ^ 1) * 16384;
            async16(Ag + ko,           &S[nbA + t * 8]);
            async16(Ag + 64 * K + ko,  &S[nbA + 4096 + t * 8]);
            async16(Bg + ko,           &S[nbB + t * 8]);
            async16(Bg + 64 * K + ko,  &S[nbB + 4096 + t * 8]);
            async16(Bg + 128 * K + ko, &S[nbB + 8192 + t * 8]);
            async16(Bg + 192 * K + ko, &S[nbB + 12288 + t * 8]);
            asm volatile("s_waitcnt vmcnt(6)" ::: "memory");   // tile kt's 6 loads landed
        } else {
            asm volatile("s_waitcnt vmcnt(0)" ::: "memory");
        }
        barrier_nodrain();                                     // A: buf[cur] ready block-wide
        const unsigned short* Ab = &S[cur * 8192];
        const unsigned short* Bb = &S[16384 + cur * 16384];
#pragma unroll
        for (int kk = 0; kk < 2; ++kk) {
            const int sw = ((kk * 4 + lk) ^ (lrow & 7)) * 8;
            s16x8 af[4], bf[4];
#pragma unroll
            for (int mf = 0; mf < 4; ++mf)
                af[mf] = *(const s16x8*)&Ab[(wm * 64 + mf * 16 + lrow) * 64 + sw];
#pragma unroll
            for (int nf = 0; nf < 4; ++nf)
                bf[nf] = *(const s16x8*)&Bb[(wn * 64 + nf * 16 + lrow) * 64 + sw];
            __builtin_amdgcn_s_setprio(1);
#pragma unroll
            for (int mf = 0; mf < 4; ++mf)
#pragma unroll
                for (int nf = 0; nf < 4; ++nf)
                    acc[mf][nf] = __builtin_amdgcn_mfma_f32_16x16x32_bf16(af[mf], bf[nf], acc[mf][nf], 0, 0, 0);
            __builtin_amdgcn_s_setprio(0);
        }
        barrier_nodrain();                                     // B: reads of buf[cur] done
    }

    const int which = bx >> 2;
    const int n0l = (bx & 3) * 256;
    if (which < 2) {
        unsigned short* dst = which ? Kb : Qs;
        const float sc = which ? 1.f : QSCALE;
#pragma unroll
        for (int mf = 0; mf < 4; ++mf)
#pragma unroll
            for (int nf = 0; nf < 4; ++nf)
#pragma unroll
                for (int r = 0; r < 4; ++r) {
                    int row = m0 + wm * 64 + mf * 16 + lk * 4 + r;
                    int col = n0l + wn * 64 + nf * 16 + lrow;
                    dst[(long)row * DM + col] = f2bf(acc[mf][nf][r] * sc);
                }
    } else {
#pragma unroll
        for (int mf = 0; mf < 4; ++mf)
#pragma unroll
            for (int nf = 0; nf < 4; ++nf) {
                const int cl = wn * 64 + nf * 16 + lrow;
                const int rl = wm * 64 + mf * 16 + lk * 4;
                ushort4 pk;
                pk.x = f2bf(acc[mf][nf][0]); pk.y = f2bf(acc[mf][nf][1]);
                pk.z = f2bf(acc[mf][nf][2]); pk.w = f2bf(acc[mf][nf][3]);
                *(ushort4*)&S[cl * 132 + rl] = pk;
            }
        __syncthreads();
        const int c = t >> 1, h2 = t & 1;
        unsigned short* vtp = Vt + (long)(n0l + c) * M_SZ + m0 + h2 * 64;
#pragma unroll
        for (int j = 0; j < 8; ++j) {
            union { struct { ushort4 a, b; } s; ix4 v; } u;
            u.s.a = *(const ushort4*)&S[c * 132 + h2 * 64 + j * 8];
            u.s.b = *(const ushort4*)&S[c * 132 + h2 * 64 + j * 8 + 4];
            *(ix4*)(vtp + j * 8) = u.v;
        }
    }
}

// ---------------- output GEMM: grid (64, 4) — same-XCD A-panel reuse ----------------
__global__ __launch_bounds__(512, 2) void gemm_out256(const unsigned short* __restrict__ A,
                                                      const unsigned short* __restrict__ W,
                                                      float* __restrict__ C) {
    __shared__ __align__(16) unsigned short S[49152];   // 96 KB

    const int t = threadIdx.x;
    const int lane = t & 63, w = t >> 6;
    const int wm = w >> 2, wn = w & 3;
    const int lrow = lane & 15, lk = lane >> 4;
    const int n0 = blockIdx.y * 256;
    const int m0 = blockIdx.x * 128;
    const int K = DM;
    const int NKT = K / 64;

    fx4 acc[4][4] = {};

    const int srow = t >> 3;
    const int cs = (t & 7) ^ (srow & 7);
    const unsigned short* Ag = A + (long)(m0 + srow) * K + cs * 8;
    const unsigned short* Bg = W + (long)(n0 + srow) * K + cs * 8;

    async16(Ag,           &S[t * 8]);
    async16(Ag + 64 * K,  &S[4096 + t * 8]);
    async16(Bg,           &S[16384 + t * 8]);
    async16(Bg + 64 * K,  &S[16384 + 4096 + t * 8]);
    async16(Bg + 128 * K, &S[16384 + 8192 + t * 8]);
    async16(Bg + 192 * K, &S[16384 + 12288 + t * 8]);

    for (int kt = 0; kt < NKT; ++kt) {
        const int cur = kt & 1;
        if (kt + 1 < NKT) {
            const int ko = (kt + 1) * 64;
            const int nbA = (cur ^ 1) * 8192;
            const int nbB = 16384 + (cur ^ 1) * 16384;
            async16(Ag + ko,           &S[nbA + t * 8]);
            async16(Ag + 64 * K + ko,  &S[nbA + 4096 + t * 8]);
            async16(Bg + ko,           &S[nbB + t * 8]);
            async16(Bg + 64 * K + ko,  &S[nbB + 4096 + t * 8]);
            async16(Bg + 128 * K + ko, &S[nbB + 8192 + t * 8]);
            async16(Bg + 192 * K + ko, &S[nbB + 12288 + t * 8]);
            asm volatile("s_waitcnt vmcnt(6)" ::: "memory");
        } else {
            asm volatile("s_waitcnt vmcnt(0)" ::: "memory");
        }
        barrier_nodrain();
        const unsigned short* Ab = &S[cur * 8192];
        const unsigned short* Bb = &S[16384 + cur * 16384];
#pragma unroll
        for (int kk = 0; kk < 2; ++kk) {
            const int sw = ((kk * 4 + lk) ^ (lrow & 7)) * 8;
            s16x8 af[4], bf[4];
#pragma unroll
            for (int mf = 0; mf < 4; ++mf)
                af[mf] = *(const s16x8*)&Ab[(wm * 64 + mf * 16 + lrow) * 64 + sw];
#pragma unroll
            for (int nf = 0; nf < 4; ++nf)
                bf[nf] = *(const s16x8*)&Bb[(wn * 64 + nf * 16 + lrow) * 64 + sw];
            __builtin_amdgcn_s_setprio(1);
#pragma unroll
            for (int mf = 0; mf < 4; ++mf)
#pragma unroll
                for (int nf = 0; nf < 4; ++nf)
                    acc[mf][nf] = __builtin_amdgcn_mfma_f32_16x16x32_bf16(af[mf], bf[nf], acc[mf][nf], 0, 0, 0);
            __builtin_amdgcn_s_setprio(0);
        }
        barrier_nodrain();
    }

#pragma unroll
    for (int mf = 0; mf < 4; ++mf)
#pragma unroll
        for (int nf = 0; nf < 4; ++nf)
#pragma unroll
            for (int r = 0; r < 4; ++r) {
                int row = m0 + wm * 64 + mf * 16 + lk * 4 + r;
                int col = n0 + wn * 64 + nf * 16 + lrow;
                C[(long)row * DM + col] = acc[mf][nf][r];
            }
}

// ---------------- Flash attention: MFMA-ones row-sum, NO setprio (R16-verified 81.3us) ----------------
__global__ __launch_bounds__(256, 4) void attn_kernel(const unsigned short* __restrict__ Q,
                                                      const unsigned short* __restrict__ Kb,
                                                      const unsigned short* __restrict__ Vt,
                                                      unsigned short* __restrict__ O) {
    __shared__ __align__(16) unsigned short Ks[2][64 * 64];   // 16 KB
    __shared__ __align__(16) unsigned short Vs[2][64 * 64];   // 16 KB
    __shared__ __align__(16) unsigned short Pl[4][16 * 64];   //  8 KB  (total 40960 = 4 blk/CU)

    const int t = threadIdx.x;
    const int lane = t & 63, w = t >> 6;
    const int lrow = lane & 15, lk = lane >> 4;
    const int hb = blockIdx.x;
    const int h = hb & 15, b = hb >> 4;
    const int qb = 15 - blockIdx.y;                // heavy blocks dispatch first
    const int row0 = b * T_SZ;
    const int q0w = qb * 128 + w * 32;

    s16x8 qf[2][2];
#pragma unroll
    for (int hh = 0; hh < 2; ++hh) {
        const unsigned short* qp = Q + (long)(row0 + q0w + hh * 16 + lrow) * DM + h * DK + lk * 8;
        qf[hh][0] = *(const s16x8*)qp;
        qf[hh][1] = *(const s16x8*)(qp + 32);
    }

    const short onebf = (short)0x3F80;             // bf16 1.0
    const s16x8 ones = {onebf, onebf, onebf, onebf, onebf, onebf, onebf, onebf};

    fx4 acc[2][4] = {};
    fx4 suml[2] = {};                              // MFMA row-sums (denominator)
    float mrun[2] = {NINF, NINF};

    const int srow = t >> 3;                               // 0..31
    const int chk = (t & 7) ^ (srow & 7);                  // source pre-swizzle
    const unsigned short* Kg = Kb + (long)(row0 + srow) * DM + h * DK + chk * 8;
    const unsigned short* Vg = Vt + (long)(h * DK + srow) * M_SZ + row0 + chk * 8;
    unsigned short* Kl = &Ks[0][t * 8];
    unsigned short* Vl = &Vs[0][t * 8];

    const int nt = 2 * qb + 2;

    async16(Kg, Kl);
    async16(Kg + 32 * DM, Kl + 2048);
    async16(Vg, Vl);
    async16(Vg + 32 * (long)M_SZ, Vl + 2048);
    asm volatile("s_waitcnt vmcnt(0)" ::: "memory");
    __syncthreads();

    for (int kt = 0; kt < nt; ++kt) {
        const int cur = kt & 1;
        const bool pre = (kt + 1 < nt);
        if (pre) {
            const long koff = (long)(kt + 1) * 64 * DM;
            const int voff = (kt + 1) * 64;
            async16(Kg + koff, Kl + (cur ^ 1) * 4096);
            async16(Kg + koff + 32 * DM, Kl + (cur ^ 1) * 4096 + 2048);
            async16(Vg + voff, Vl + (cur ^ 1) * 4096);
            async16(Vg + voff + 32 * (long)M_SZ, Vl + (cur ^ 1) * 4096 + 2048);
        }
        const int kv0 = kt * 64;
        if (kv0 <= q0w + 31) {
            const char* ksb = (const char*)&Ks[cur][0];
            float p[2][4][4];
#pragma unroll
            for (int sub = 0; sub < 4; ++sub) {
                const int kv0s = kv0 + sub * 16;
                if (kv0s <= q0w + 31) {          // half 1 active
                    const int rb = (sub * 16 + lrow) << 7;
                    const int sw = (lrow & 7) << 4;
                    const s16x8 kf0 = *(const s16x8*)(ksb + (rb + ((lk * 16) ^ sw)));
                    const s16x8 kf1 = *(const s16x8*)(ksb + (rb + ((64 + lk * 16) ^ sw)));
                    fx4 s1 = {};
                    s1 = __builtin_amdgcn_mfma_f32_16x16x32_bf16(kf0, qf[1][0], s1, 0, 0, 0);
                    s1 = __builtin_amdgcn_mfma_f32_16x16x32_bf16(kf1, qf[1][1], s1, 0, 0, 0);
                    if (kv0s + 15 > q0w + 16) {
#pragma unroll
                        for (int r = 0; r < 4; ++r)
                            if (kv0s + lk * 4 + r > q0w + 16 + lrow) s1[r] = NINF;
                    }
#pragma unroll
                    for (int r = 0; r < 4; ++r) p[1][sub][r] = s1[r];
                    if (kv0s <= q0w + 15) {      // half 0 active
                        fx4 s0 = {};
                        s0 = __builtin_amdgcn_mfma_f32_16x16x32_bf16(kf0, qf[0][0], s0, 0, 0, 0);
                        s0 = __builtin_amdgcn_mfma_f32_16x16x32_bf16(kf1, qf[0][1], s0, 0, 0, 0);
                        if (kv0s + 15 > q0w) {
#pragma unroll
                            for (int r = 0; r < 4; ++r)
                                if (kv0s + lk * 4 + r > q0w + lrow) s0[r] = NINF;
                        }
#pragma unroll
                        for (int r = 0; r < 4; ++r) p[0][sub][r] = s0[r];
                    } else {
#pragma unroll
                        for (int r = 0; r < 4; ++r) p[0][sub][r] = NINF;
                    }
                } else {
#pragma unroll
                    for (int r = 0; r < 4; ++r) { p[0][sub][r] = NINF; p[1][sub][r] = NINF; }
                }
            }
            // ---- online softmax per half: max3 tree, branch-local shuffles ----
#pragma unroll
            for (int hh = 0; hh < 2; ++hh) {
                float t0 = MAX3(p[hh][0][0], p[hh][0][1], p[hh][0][2]);
                float t1 = MAX3(p[hh][0][3], p[hh][1][0], p[hh][1][1]);
                float t2 = MAX3(p[hh][1][2], p[hh][1][3], p[hh][2][0]);
                float t3 = MAX3(p[hh][2][1], p[hh][2][2], p[hh][2][3]);
                float t4 = MAX3(p[hh][3][0], p[hh][3][1], p[hh][3][2]);
                float pm = fmaxf(MAX3(MAX3(t0, t1, t2), t3, t4), p[hh][3][3]);
                if (__any(pm > mrun[hh] + 8.f)) {        // rare: full row-max + rescale
                    pm = fmaxf(pm, __shfl_xor(pm, 16));
                    pm = fmaxf(pm, __shfl_xor(pm, 32));
                    const float mnew = fmaxf(mrun[hh], pm);
                    const float sc = exp2f(mrun[hh] - mnew);
                    mrun[hh] = mnew;
#pragma unroll
                    for (int r = 0; r < 4; ++r) {
                        const float scr = __shfl(sc, lk * 4 + r);
                        acc[hh][0][r] *= scr; acc[hh][1][r] *= scr;
                        acc[hh][2][r] *= scr; acc[hh][3][r] *= scr;
                        suml[hh][r] *= scr;
                    }
                }
#pragma unroll
                for (int sub = 0; sub < 4; ++sub)
#pragma unroll
                    for (int r = 0; r < 4; ++r)
                        p[hh][sub][r] = exp2f(p[hh][sub][r] - mrun[hh]);
            }
            s16x8 pf[2][2];
#pragma unroll
            for (int hh = 0; hh < 2; ++hh) {
#pragma unroll
                for (int sub = 0; sub < 4; ++sub) {
                    uint2 pw;
                    pw.x = cvtpk(p[hh][sub][0], p[hh][sub][1]);
                    pw.y = cvtpk(p[hh][sub][2], p[hh][sub][3]);
                    *(uint2*)&Pl[w][lrow * 64 + ((sub * 16 + lk * 4) ^ ((lrow & 7) << 3))] = pw;
                }
                pf[hh][0] = *(const s16x8*)&Pl[w][lrow * 64 + ((lk * 8) ^ ((lrow & 7) << 3))];
                pf[hh][1] = *(const s16x8*)&Pl[w][lrow * 64 + ((32 + lk * 8) ^ ((lrow & 7) << 3))];
            }
#pragma unroll
            for (int s = 0; s < 2; ++s) {
                if (kv0 + s * 32 <= q0w + 31) {
                    const bool h0a = (kv0 + s * 32 <= q0w + 15);
                    if (h0a)
                        suml[0] = __builtin_amdgcn_mfma_f32_16x16x32_bf16(pf[0][s], ones, suml[0], 0, 0, 0);
                    suml[1] = __builtin_amdgcn_mfma_f32_16x16x32_bf16(pf[1][s], ones, suml[1], 0, 0, 0);
#pragma unroll
                    for (int nf = 0; nf < 4; ++nf) {
                        const int d = nf * 16 + lrow;
                        const s16x8 vf = *(const s16x8*)&Vs[cur][d * 64 + (((s * 4 + lk) ^ (lrow & 7)) << 3)];
                        if (h0a)
                            acc[0][nf] = __builtin_amdgcn_mfma_f32_16x16x32_bf16(pf[0][s], vf, acc[0][nf], 0, 0, 0);
                        acc[1][nf] = __builtin_amdgcn_mfma_f32_16x16x32_bf16(pf[1][s], vf, acc[1][nf], 0, 0, 0);
                    }
                }
            }
        }
        asm volatile("s_waitcnt vmcnt(0)" ::: "memory");
        __syncthreads();
    }

    // ---- epilogue: per-lane divide by MFMA row-sum (no shuffles) ----
#pragma unroll
    for (int hh = 0; hh < 2; ++hh) {
        float linv[4];
#pragma unroll
        for (int r = 0; r < 4; ++r) linv[r] = 1.f / suml[hh][r];
        unsigned short* op = O + (long)(row0 + q0w + hh * 16) * DM + h * DK;
#pragma unroll
        for (int nf = 0; nf < 4; ++nf)
#pragma unroll
            for (int r = 0; r < 4; ++r)
                op[(long)(lk * 4 + r) * DM + nf * 16 + lrow] = f2bf(acc[hh][nf][r] * linv[r]);
    }
}

extern "C" void kernel_launch(void* const* d_in, const int* in_sizes, int n_in,
                              void* d_out, int out_size, void* d_ws, size_t ws_size,
                              hipStream_t stream) {
    const float* x  = (const float*)d_in[0];
    const float* Wq = (const float*)d_in[1];
    const float* Wk = (const float*)d_in[2];
    const float* Wv = (const float*)d_in[3];
    const float* Wo = (const float*)d_in[4];
    float* out = (float*)d_out;

    unsigned short* wsu = (unsigned short*)d_ws;
    unsigned short* xb  = wsu;                  // 8,388,608 elems
    unsigned short* wqb = xb + 8388608;         // 4 x 1,048,576 (contiguous: Wq,Wk,Wv,Wo)
    unsigned short* wob = wqb + 3 * 1048576;
    unsigned short* Qs  = wob + 1048576;        // 8,388,608
    unsigned short* Ob  = Qs + 8388608;         // 8,388,608 (attn output O)

    unsigned short* Kb = (unsigned short*)d_out;        // 16MB in d_out
    unsigned short* Vt = Kb + 8388608;                  // 16MB in d_out (V transposed)

    cast_all<<<dim3(512, 5), 256, 0, stream>>>(x, Wq, Wk, Wv, Wo, xb, wqb);

    // fused Q/K/V projection: m-tiles on x (same-XCD A-panel reuse), 12 col/which tiles on y
    gemm_qkv256<<<dim3(M_SZ / 128, 12), 512, 0, stream>>>(xb, wqb, Qs, Kb, Vt);

    dim3 agrid(64, 16);                // x = (b,h) -> fixed XCD; y -> qb (heavy first)
    attn_kernel<<<agrid, 256, 0, stream>>>(Qs, Kb, Vt, Ob);

    // output projection: m-tiles on x
    gemm_out256<<<dim3(M_SZ / 128, DM / 256), 512, 0, stream>>>(Ob, wob, out);
}

// Round 20
// 171.096 us; speedup vs baseline: 1.0547x; 1.0071x over previous
//
#include <hip/hip_runtime.h>

typedef __attribute__((ext_vector_type(8))) short s16x8;
typedef __attribute__((ext_vector_type(4))) float fx4;
typedef __attribute__((ext_vector_type(4))) int ix4;

#define B_SZ 4
#define T_SZ 2048
#define DM 1024
#define NH 16
#define DK 64
#define M_SZ (B_SZ * T_SZ)   // 8192
#define NINF (-__builtin_inff())
#define QSCALE (0.125f * 1.44269504088896340736f)
#define MAX3(a,b,c) fmaxf(fmaxf(a,b),c)

__device__ __forceinline__ unsigned short f2bf(float f) {
    unsigned int u = __float_as_uint(f);
    unsigned int r = u + 0x7fffu + ((u >> 16) & 1u);
    return (unsigned short)(r >> 16);
}

__device__ __forceinline__ unsigned cvtpk(float lo, float hi) {
    unsigned r;
    asm("v_cvt_pk_bf16_f32 %0, %1, %2" : "=v"(r) : "v"(lo), "v"(hi));
    return r;
}

__device__ __forceinline__ void async16(const unsigned short* g, unsigned short* l) {
    __builtin_amdgcn_global_load_lds(
        (const __attribute__((address_space(1))) unsigned int*)g,
        (__attribute__((address_space(3))) unsigned int*)l, 16, 0, 0);
}

// raw workgroup barrier WITHOUT the __syncthreads vmcnt(0) drain.
__device__ __forceinline__ void barrier_nodrain() {
    asm volatile("" ::: "memory");
    __builtin_amdgcn_s_barrier();
    asm volatile("" ::: "memory");
}

// ---------------- merged cast: y==0 -> x (8.4M), y==1..4 -> weights ----------------
__global__ void cast_all(const float* __restrict__ x,
                         const float* __restrict__ s1, const float* __restrict__ s2,
                         const float* __restrict__ s3, const float* __restrict__ s4,
                         unsigned short* __restrict__ xb, unsigned short* __restrict__ wb) {
    const int y = blockIdx.y;
    const float* s;
    unsigned short* d;
    int n;
    if (y == 0) { s = x; d = xb; n = M_SZ * DM; }
    else {
        s = (y == 1) ? s1 : (y == 2) ? s2 : (y == 3) ? s3 : s4;
        d = wb + (size_t)(y - 1) * (DM * DM);
        n = DM * DM;
    }
    int i = (blockIdx.x * blockDim.x + threadIdx.x) * 4;
    int stride = gridDim.x * blockDim.x * 4;
    for (; i + 3 < n; i += stride) {
        float4 v = *(const float4*)(s + i);
        ushort4 o;
        o.x = f2bf(v.x); o.y = f2bf(v.y); o.z = f2bf(v.z); o.w = f2bf(v.w);
        *(ushort4*)(d + i) = o;
    }
}

// ---------------- fused QKV GEMM: 128x256 tile, BK=64, cross-barrier 2-buffer pipeline ----------------
// Grid (64, 12): m-tile on blockIdx.x -> all 12 consumers of an A-panel on ONE XCD.
__global__ __launch_bounds__(512, 2) void gemm_qkv256(const unsigned short* __restrict__ A,
                                                      const unsigned short* __restrict__ W,
                                                      unsigned short* __restrict__ Qs,
                                                      unsigned short* __restrict__ Kb,
                                                      unsigned short* __restrict__ Vt) {
    __shared__ __align__(16) unsigned short S[49152];   // 96 KB

    const int t = threadIdx.x;
    const int lane = t & 63, w = t >> 6;
    const int wm = w >> 2, wn = w & 3;          // 2 x 4 wave grid
    const int lrow = lane & 15, lk = lane >> 4;
    const int bx = blockIdx.y;                  // 0..11 (which*4 + n-col tile)
    const int m0 = blockIdx.x * 128;
    const int K = DM;
    const int NKT = K / 64;                     // 16

    fx4 acc[4][4] = {};

    const int srow = t >> 3;                    // 0..63
    const int cs = (t & 7) ^ (srow & 7);        // swizzled source chunk
    const unsigned short* Ag = A + (long)(m0 + srow) * K + cs * 8;
    const unsigned short* Bg = W + (long)(bx * 256 + srow) * K + cs * 8;

    async16(Ag,           &S[t * 8]);
    async16(Ag + 64 * K,  &S[4096 + t * 8]);
    async16(Bg,           &S[16384 + t * 8]);
    async16(Bg + 64 * K,  &S[16384 + 4096 + t * 8]);
    async16(Bg + 128 * K, &S[16384 + 8192 + t * 8]);
    async16(Bg + 192 * K, &S[16384 + 12288 + t * 8]);

    for (int kt = 0; kt < NKT; ++kt) {
        const int cur = kt & 1;
        if (kt + 1 < NKT) {
            const int ko = (kt + 1) * 64;
            const int nbA = (cur ^ 1) * 8192;
            const int nbB = 16384 + (cur ^ 1) * 16384;
            async16(Ag + ko,           &S[nbA + t * 8]);
            async16(Ag + 64 * K + ko,  &S[nbA + 4096 + t * 8]);
            async16(Bg + ko,           &S[nbB + t * 8]);
            async16(Bg + 64 * K + ko,  &S[nbB + 4096 + t * 8]);
            async16(Bg + 128 * K + ko, &S[nbB + 8192 + t * 8]);
            async16(Bg + 192 * K + ko, &S[nbB + 12288 + t * 8]);
            asm volatile("s_waitcnt vmcnt(6)" ::: "memory");   // tile kt's 6 loads landed
        } else {
            asm volatile("s_waitcnt vmcnt(0)" ::: "memory");
        }
        barrier_nodrain();                                     // A: buf[cur] ready block-wide
        const unsigned short* Ab = &S[cur * 8192];
        const unsigned short* Bb = &S[16384 + cur * 16384];
#pragma unroll
        for (int kk = 0; kk < 2; ++kk) {
            const int sw = ((kk * 4 + lk) ^ (lrow & 7)) * 8;
            s16x8 af[4], bf[4];
#pragma unroll
            for (int mf = 0; mf < 4; ++mf)
                af[mf] = *(const s16x8*)&Ab[(wm * 64 + mf * 16 + lrow) * 64 + sw];
#pragma unroll
            for (int nf = 0; nf < 4; ++nf)
                bf[nf] = *(const s16x8*)&Bb[(wn * 64 + nf * 16 + lrow) * 64 + sw];
            __builtin_amdgcn_s_setprio(1);
#pragma unroll
            for (int mf = 0; mf < 4; ++mf)
#pragma unroll
                for (int nf = 0; nf < 4; ++nf)
                    acc[mf][nf] = __builtin_amdgcn_mfma_f32_16x16x32_bf16(af[mf], bf[nf], acc[mf][nf], 0, 0, 0);
            __builtin_amdgcn_s_setprio(0);
        }
        barrier_nodrain();                                     // B: reads of buf[cur] done
    }

    const int which = bx >> 2;
    const int n0l = (bx & 3) * 256;
    if (which < 2) {
        unsigned short* dst = which ? Kb : Qs;
        const float sc = which ? 1.f : QSCALE;
#pragma unroll
        for (int mf = 0; mf < 4; ++mf)
#pragma unroll
            for (int nf = 0; nf < 4; ++nf)
#pragma unroll
                for (int r = 0; r < 4; ++r) {
                    int row = m0 + wm * 64 + mf * 16 + lk * 4 + r;
                    int col = n0l + wn * 64 + nf * 16 + lrow;
                    dst[(long)row * DM + col] = f2bf(acc[mf][nf][r] * sc);
                }
    } else {
#pragma unroll
        for (int mf = 0; mf < 4; ++mf)
#pragma unroll
            for (int nf = 0; nf < 4; ++nf) {
                const int cl = wn * 64 + nf * 16 + lrow;
                const int rl = wm * 64 + mf * 16 + lk * 4;
                ushort4 pk;
                pk.x = f2bf(acc[mf][nf][0]); pk.y = f2bf(acc[mf][nf][1]);
                pk.z = f2bf(acc[mf][nf][2]); pk.w = f2bf(acc[mf][nf][3]);
                *(ushort4*)&S[cl * 132 + rl] = pk;
            }
        __syncthreads();
        const int c = t >> 1, h2 = t & 1;
        unsigned short* vtp = Vt + (long)(n0l + c) * M_SZ + m0 + h2 * 64;
#pragma unroll
        for (int j = 0; j < 8; ++j) {
            union { struct { ushort4 a, b; } s; ix4 v; } u;
            u.s.a = *(const ushort4*)&S[c * 132 + h2 * 64 + j * 8];
            u.s.b = *(const ushort4*)&S[c * 132 + h2 * 64 + j * 8 + 4];
            *(ix4*)(vtp + j * 8) = u.v;
        }
    }
}

// ---------------- output GEMM: grid (64, 4) — same-XCD A-panel reuse ----------------
__global__ __launch_bounds__(512, 2) void gemm_out256(const unsigned short* __restrict__ A,
                                                      const unsigned short* __restrict__ W,
                                                      float* __restrict__ C) {
    __shared__ __align__(16) unsigned short S[49152];   // 96 KB

    const int t = threadIdx.x;
    const int lane = t & 63, w = t >> 6;
    const int wm = w >> 2, wn = w & 3;
    const int lrow = lane & 15, lk = lane >> 4;
    const int n0 = blockIdx.y * 256;
    const int m0 = blockIdx.x * 128;
    const int K = DM;
    const int NKT = K / 64;

    fx4 acc[4][4] = {};

    const int srow = t >> 3;
    const int cs = (t & 7) ^ (srow & 7);
    const unsigned short* Ag = A + (long)(m0 + srow) * K + cs * 8;
    const unsigned short* Bg = W + (long)(n0 + srow) * K + cs * 8;

    async16(Ag,           &S[t * 8]);
    async16(Ag + 64 * K,  &S[4096 + t * 8]);
    async16(Bg,           &S[16384 + t * 8]);
    async16(Bg + 64 * K,  &S[16384 + 4096 + t * 8]);
    async16(Bg + 128 * K, &S[16384 + 8192 + t * 8]);
    async16(Bg + 192 * K, &S[16384 + 12288 + t * 8]);

    for (int kt = 0; kt < NKT; ++kt) {
        const int cur = kt & 1;
        if (kt + 1 < NKT) {
            const int ko = (kt + 1) * 64;
            const int nbA = (cur ^ 1) * 8192;
            const int nbB = 16384 + (cur ^ 1) * 16384;
            async16(Ag + ko,           &S[nbA + t * 8]);
            async16(Ag + 64 * K + ko,  &S[nbA + 4096 + t * 8]);
            async16(Bg + ko,           &S[nbB + t * 8]);
            async16(Bg + 64 * K + ko,  &S[nbB + 4096 + t * 8]);
            async16(Bg + 128 * K + ko, &S[nbB + 8192 + t * 8]);
            async16(Bg + 192 * K + ko, &S[nbB + 12288 + t * 8]);
            asm volatile("s_waitcnt vmcnt(6)" ::: "memory");
        } else {
            asm volatile("s_waitcnt vmcnt(0)" ::: "memory");
        }
        barrier_nodrain();
        const unsigned short* Ab = &S[cur * 8192];
        const unsigned short* Bb = &S[16384 + cur * 16384];
#pragma unroll
        for (int kk = 0; kk < 2; ++kk) {
            const int sw = ((kk * 4 + lk) ^ (lrow & 7)) * 8;
            s16x8 af[4], bf[4];
#pragma unroll
            for (int mf = 0; mf < 4; ++mf)
                af[mf] = *(const s16x8*)&Ab[(wm * 64 + mf * 16 + lrow) * 64 + sw];
#pragma unroll
            for (int nf = 0; nf < 4; ++nf)
                bf[nf] = *(const s16x8*)&Bb[(wn * 64 + nf * 16 + lrow) * 64 + sw];
            __builtin_amdgcn_s_setprio(1);
#pragma unroll
            for (int mf = 0; mf < 4; ++mf)
#pragma unroll
                for (int nf = 0; nf < 4; ++nf)
                    acc[mf][nf] = __builtin_amdgcn_mfma_f32_16x16x32_bf16(af[mf], bf[nf], acc[mf][nf], 0, 0, 0);
            __builtin_amdgcn_s_setprio(0);
        }
        barrier_nodrain();
    }

#pragma unroll
    for (int mf = 0; mf < 4; ++mf)
#pragma unroll
        for (int nf = 0; nf < 4; ++nf)
#pragma unroll
            for (int r = 0; r < 4; ++r) {
                int row = m0 + wm * 64 + mf * 16 + lk * 4 + r;
                int col = n0 + wn * 64 + nf * 16 + lrow;
                C[(long)row * DM + col] = acc[mf][nf][r];
            }
}

// ---------------- Flash attention: counted vmcnt(4) + raw-barrier pipeline (GEMM-verified pattern) ----------------
__global__ __launch_bounds__(256, 4) void attn_kernel(const unsigned short* __restrict__ Q,
                                                      const unsigned short* __restrict__ Kb,
                                                      const unsigned short* __restrict__ Vt,
                                                      unsigned short* __restrict__ O) {
    __shared__ __align__(16) unsigned short Ks[2][64 * 64];   // 16 KB
    __shared__ __align__(16) unsigned short Vs[2][64 * 64];   // 16 KB
    __shared__ __align__(16) unsigned short Pl[4][16 * 64];   //  8 KB  (total 40960 = 4 blk/CU)

    const int t = threadIdx.x;
    const int lane = t & 63, w = t >> 6;
    const int lrow = lane & 15, lk = lane >> 4;
    const int hb = blockIdx.x;
    const int h = hb & 15, b = hb >> 4;
    const int qb = 15 - blockIdx.y;                // heavy blocks dispatch first
    const int row0 = b * T_SZ;
    const int q0w = qb * 128 + w * 32;

    s16x8 qf[2][2];
#pragma unroll
    for (int hh = 0; hh < 2; ++hh) {
        const unsigned short* qp = Q + (long)(row0 + q0w + hh * 16 + lrow) * DM + h * DK + lk * 8;
        qf[hh][0] = *(const s16x8*)qp;
        qf[hh][1] = *(const s16x8*)(qp + 32);
    }

    const short onebf = (short)0x3F80;             // bf16 1.0
    const s16x8 ones = {onebf, onebf, onebf, onebf, onebf, onebf, onebf, onebf};

    fx4 acc[2][4] = {};
    fx4 suml[2] = {};                              // MFMA row-sums (denominator)
    float mrun[2] = {NINF, NINF};

    const int srow = t >> 3;                               // 0..31
    const int chk = (t & 7) ^ (srow & 7);                  // source pre-swizzle
    const unsigned short* Kg = Kb + (long)(row0 + srow) * DM + h * DK + chk * 8;
    const unsigned short* Vg = Vt + (long)(h * DK + srow) * M_SZ + row0 + chk * 8;
    unsigned short* Kl = &Ks[0][t * 8];
    unsigned short* Vl = &Vs[0][t * 8];

    const int nt = 2 * qb + 2;

    // prologue: issue tile 0 (first loop iteration waits on it via vmcnt)
    async16(Kg, Kl);
    async16(Kg + 32 * DM, Kl + 2048);
    async16(Vg, Vl);
    async16(Vg + 32 * (long)M_SZ, Vl + 2048);

    for (int kt = 0; kt < nt; ++kt) {
        const int cur = kt & 1;
        if (kt + 1 < nt) {
            const long koff = (long)(kt + 1) * 64 * DM;
            const int voff = (kt + 1) * 64;
            async16(Kg + koff, Kl + (cur ^ 1) * 4096);
            async16(Kg + koff + 32 * DM, Kl + (cur ^ 1) * 4096 + 2048);
            async16(Vg + voff, Vl + (cur ^ 1) * 4096);
            async16(Vg + voff + 32 * (long)M_SZ, Vl + (cur ^ 1) * 4096 + 2048);
            asm volatile("s_waitcnt vmcnt(4)" ::: "memory");   // tile kt's 4 loads landed
        } else {
            asm volatile("s_waitcnt vmcnt(0)" ::: "memory");
        }
        barrier_nodrain();                                     // A: buf[cur] ready block-wide
        const int kv0 = kt * 64;
        if (kv0 <= q0w + 31) {
            const char* ksb = (const char*)&Ks[cur][0];
            float p[2][4][4];
#pragma unroll
            for (int sub = 0; sub < 4; ++sub) {
                const int kv0s = kv0 + sub * 16;
                if (kv0s <= q0w + 31) {          // half 1 active
                    const int rb = (sub * 16 + lrow) << 7;
                    const int sw = (lrow & 7) << 4;
                    const s16x8 kf0 = *(const s16x8*)(ksb + (rb + ((lk * 16) ^ sw)));
                    const s16x8 kf1 = *(const s16x8*)(ksb + (rb + ((64 + lk * 16) ^ sw)));
                    fx4 s1 = {};
                    s1 = __builtin_amdgcn_mfma_f32_16x16x32_bf16(kf0, qf[1][0], s1, 0, 0, 0);
                    s1 = __builtin_amdgcn_mfma_f32_16x16x32_bf16(kf1, qf[1][1], s1, 0, 0, 0);
                    if (kv0s + 15 > q0w + 16) {
#pragma unroll
                        for (int r = 0; r < 4; ++r)
                            if (kv0s + lk * 4 + r > q0w + 16 + lrow) s1[r] = NINF;
                    }
#pragma unroll
                    for (int r = 0; r < 4; ++r) p[1][sub][r] = s1[r];
                    if (kv0s <= q0w + 15) {      // half 0 active
                        fx4 s0 = {};
                        s0 = __builtin_amdgcn_mfma_f32_16x16x32_bf16(kf0, qf[0][0], s0, 0, 0, 0);
                        s0 = __builtin_amdgcn_mfma_f32_16x16x32_bf16(kf1, qf[0][1], s0, 0, 0, 0);
                        if (kv0s + 15 > q0w) {
#pragma unroll
                            for (int r = 0; r < 4; ++r)
                                if (kv0s + lk * 4 + r > q0w + lrow) s0[r] = NINF;
                        }
#pragma unroll
                        for (int r = 0; r < 4; ++r) p[0][sub][r] = s0[r];
                    } else {
#pragma unroll
                        for (int r = 0; r < 4; ++r) p[0][sub][r] = NINF;
                    }
                } else {
#pragma unroll
                    for (int r = 0; r < 4; ++r) { p[0][sub][r] = NINF; p[1][sub][r] = NINF; }
                }
            }
            // ---- online softmax per half: max3 tree, branch-local shuffles ----
#pragma unroll
            for (int hh = 0; hh < 2; ++hh) {
                float t0 = MAX3(p[hh][0][0], p[hh][0][1], p[hh][0][2]);
                float t1 = MAX3(p[hh][0][3], p[hh][1][0], p[hh][1][1]);
                float t2 = MAX3(p[hh][1][2], p[hh][1][3], p[hh][2][0]);
                float t3 = MAX3(p[hh][2][1], p[hh][2][2], p[hh][2][3]);
                float t4 = MAX3(p[hh][3][0], p[hh][3][1], p[hh][3][2]);
                float pm = fmaxf(MAX3(MAX3(t0, t1, t2), t3, t4), p[hh][3][3]);
                if (__any(pm > mrun[hh] + 8.f)) {        // rare: full row-max + rescale
                    pm = fmaxf(pm, __shfl_xor(pm, 16));
                    pm = fmaxf(pm, __shfl_xor(pm, 32));
                    const float mnew = fmaxf(mrun[hh], pm);
                    const float sc = exp2f(mrun[hh] - mnew);
                    mrun[hh] = mnew;
#pragma unroll
                    for (int r = 0; r < 4; ++r) {
                        const float scr = __shfl(sc, lk * 4 + r);
                        acc[hh][0][r] *= scr; acc[hh][1][r] *= scr;
                        acc[hh][2][r] *= scr; acc[hh][3][r] *= scr;
                        suml[hh][r] *= scr;
                    }
                }
#pragma unroll
                for (int sub = 0; sub < 4; ++sub)
#pragma unroll
                    for (int r = 0; r < 4; ++r)
                        p[hh][sub][r] = exp2f(p[hh][sub][r] - mrun[hh]);
            }
            s16x8 pf[2][2];
#pragma unroll
            for (int hh = 0; hh < 2; ++hh) {
#pragma unroll
                for (int sub = 0; sub < 4; ++sub) {
                    uint2 pw;
                    pw.x = cvtpk(p[hh][sub][0], p[hh][sub][1]);
                    pw.y = cvtpk(p[hh][sub][2], p[hh][sub][3]);
                    *(uint2*)&Pl[w][lrow * 64 + ((sub * 16 + lk * 4) ^ ((lrow & 7) << 3))] = pw;
                }
                pf[hh][0] = *(const s16x8*)&Pl[w][lrow * 64 + ((lk * 8) ^ ((lrow & 7) << 3))];
                pf[hh][1] = *(const s16x8*)&Pl[w][lrow * 64 + ((32 + lk * 8) ^ ((lrow & 7) << 3))];
            }
#pragma unroll
            for (int s = 0; s < 2; ++s) {
                if (kv0 + s * 32 <= q0w + 31) {
                    const bool h0a = (kv0 + s * 32 <= q0w + 15);
                    if (h0a)
                        suml[0] = __builtin_amdgcn_mfma_f32_16x16x32_bf16(pf[0][s], ones, suml[0], 0, 0, 0);
                    suml[1] = __builtin_amdgcn_mfma_f32_16x16x32_bf16(pf[1][s], ones, suml[1], 0, 0, 0);
#pragma unroll
                    for (int nf = 0; nf < 4; ++nf) {
                        const int d = nf * 16 + lrow;
                        const s16x8 vf = *(const s16x8*)&Vs[cur][d * 64 + (((s * 4 + lk) ^ (lrow & 7)) << 3)];
                        if (h0a)
                            acc[0][nf] = __builtin_amdgcn_mfma_f32_16x16x32_bf16(pf[0][s], vf, acc[0][nf], 0, 0, 0);
                        acc[1][nf] = __builtin_amdgcn_mfma_f32_16x16x32_bf16(pf[1][s], vf, acc[1][nf], 0, 0, 0);
                    }
                }
            }
        }
        barrier_nodrain();                                     // B: reads of buf[cur] done
    }

    // ---- epilogue: per-lane divide by MFMA row-sum (no shuffles) ----
#pragma unroll
    for (int hh = 0; hh < 2; ++hh) {
        float linv[4];
#pragma unroll
        for (int r = 0; r < 4; ++r) linv[r] = 1.f / suml[hh][r];
        unsigned short* op = O + (long)(row0 + q0w + hh * 16) * DM + h * DK;
#pragma unroll
        for (int nf = 0; nf < 4; ++nf)
#pragma unroll
            for (int r = 0; r < 4; ++r)
                op[(long)(lk * 4 + r) * DM + nf * 16 + lrow] = f2bf(acc[hh][nf][r] * linv[r]);
    }
}

extern "C" void kernel_launch(void* const* d_in, const int* in_sizes, int n_in,
                              void* d_out, int out_size, void* d_ws, size_t ws_size,
                              hipStream_t stream) {
    const float* x  = (const float*)d_in[0];
    const float* Wq = (const float*)d_in[1];
    const float* Wk = (const float*)d_in[2];
    const float* Wv = (const float*)d_in[3];
    const float* Wo = (const float*)d_in[4];
    float* out = (float*)d_out;

    unsigned short* wsu = (unsigned short*)d_ws;
    unsigned short* xb  = wsu;                  // 8,388,608 elems
    unsigned short* wqb = xb + 8388608;         // 4 x 1,048,576 (contiguous: Wq,Wk,Wv,Wo)
    unsigned short* wob = wqb + 3 * 1048576;
    unsigned short* Qs  = wob + 1048576;        // 8,388,608
    unsigned short* Ob  = Qs + 8388608;         // 8,388,608 (attn output O)

    unsigned short* Kb = (unsigned short*)d_out;        // 16MB in d_out
    unsigned short* Vt = Kb + 8388608;                  // 16MB in d_out (V transposed)

    cast_all<<<dim3(512, 5), 256, 0, stream>>>(x, Wq, Wk, Wv, Wo, xb, wqb);

    // fused Q/K/V projection: m-tiles on x (same-XCD A-panel reuse), 12 col/which tiles on y
    gemm_qkv256<<<dim3(M_SZ / 128, 12), 512, 0, stream>>>(xb, wqb, Qs, Kb, Vt);

    dim3 agrid(64, 16);                // x = (b,h) -> fixed XCD; y -> qb (heavy first)
    attn_kernel<<<agrid, 256, 0, stream>>>(Qs, Kb, Vt, Ob);

    // output projection: m-tiles on x
    gemm_out256<<<dim3(M_SZ / 128, DM / 256), 512, 0, stream>>>(Ob, wob, out);
}